// Round 3
// baseline (433.010 us; speedup 1.0000x reference)
//
#include <hip/hip_runtime.h>

// ---------------------------------------------------------------------------
// TextGCN (2-layer GCN, eval mode) on MI355X.
// Fusions:
//   * xw1_word = word @ (W_lin@W1) + (b_lin@W1)  (never materialize [N,768] x)
//   * layer 2: agg(h1@W2)[mask] == agg(h1)[mask] @ W2
// PIPELINE (short critical path, latency-bound phases overlapped):
//   memset -> k_pre(fuseGEMM || packW1 || packW2 || hist{cnt,wdeg}) ->
//   scan_reduce(+packWf) -> scan_small -> scan_final(offs,cursor,dis,selfloop)
//   -> k_main(docGEMM || wordGEMM || FILL-normalized) -> agg -> agg2m -> final
// Degrees come from the histogram pass (wdeg float atomics), so dis is known
// BEFORE fill: fill writes FINAL norm = dis[src]*w*dis[dst]; self-loop entry
// (written in scan_final) = dis[i]^2. k_degdis/k_prenorm kernels deleted.
// Fill shares k_main with the GEMMs: both are latency-bound, interleaving
// them on the CUs raises total outstanding-memory parallelism instead of
// paying the two latencies serially.
// xw1/h1 bf16 in PERMUTED column order pi(pos)=(pos&3)*16+(pos>>2) (coalesced
// 8B MFMA epilogue stores). b1 indexed via pi; packW2 k-rows permuted via pi.
// MFMA GEMM: 32 rows/wave (2 rowsets SHARE each B-fragment load -> half the
// B re-read traffic), no LDS/barriers. k0 loop unrolled x2 for MLP.
// ---------------------------------------------------------------------------

typedef __attribute__((ext_vector_type(8))) short short8;   // 8 bf16 = 4 VGPR
typedef __attribute__((ext_vector_type(4))) float float4v;  // MFMA C/D frag

__device__ __forceinline__ unsigned short f2bf(float f) {   // RNE f32->bf16
  unsigned u = __float_as_uint(f);
  return (unsigned short)((u + 0x7FFFu + ((u >> 16) & 1u)) >> 16);
}
__device__ __forceinline__ float bf2f(unsigned short u) {
  return __uint_as_float((unsigned)u << 16);
}
__device__ __forceinline__ int permcol(int p) {   // pi: pos -> true col
  return ((p & 3) << 4) | (p >> 2);
}

// pack W[K,64] fp32 -> bf16 fragment order: pack[((g*nk0+k0)*64+lane)*8+j]
// holds W[ksrc][(lane&15)+16g], ksrc = PERM ? pi(k) : k; zero past K.
template <bool PERM>
__device__ __forceinline__ void pack_w_body(const float* __restrict__ W, int K,
                                            int nk0, unsigned short* __restrict__ pack,
                                            int tid) {
  int lane = tid & 63;
  int rest = tid >> 6;
  int k0 = rest % nk0;
  int g = rest / nk0;
  int quad = lane >> 4;
  int n = (lane & 15) + g * 16;
  short8 v;
#pragma unroll
  for (int j = 0; j < 8; ++j) {
    int k = k0 * 32 + quad * 8 + j;
    int ks = PERM ? permcol(k) : k;
    float w = (k < K) ? W[(size_t)ks * 64 + n] : 0.f;
    v[j] = (short)f2bf(w);
  }
  *(short8*)(pack + (((size_t)(g * nk0 + k0) * 64 + lane) << 3)) = v;
}

// MFMA GEMM: out[R,64] = X[R,K(ldx)] @ W[K,64] (+bias). One wave = 16*RS rows;
// RS rowsets share each B-fragment load (halves B traffic at RS=2).
template <bool LAST, bool PACKED, bool BF16PERM, int RS>
__device__ __forceinline__ void mfma_gemm_body(
    const float* __restrict__ X, int ldx, const float* __restrict__ lastRow,
    const unsigned short* __restrict__ Wpack, const float* __restrict__ Wf,
    int nk0, int K, const float* __restrict__ bias,
    void* __restrict__ outv, int R, int waveIdx) {
  int r0 = waveIdx * 16 * RS;
  if (r0 >= R) return;
  const int lane = threadIdx.x & 63;
  const int quad = lane >> 4;
  const int m = lane & 15;
  const float* xrow[RS];
#pragma unroll
  for (int rs = 0; rs < RS; ++rs) {
    int row = r0 + rs * 16 + m;
    xrow[rs] = nullptr;
    if (row < R) xrow[rs] = (LAST && row == R - 1) ? lastRow : X + (size_t)row * ldx;
  }

  float4v acc[RS][4];
#pragma unroll
  for (int rs = 0; rs < RS; ++rs)
#pragma unroll
    for (int g = 0; g < 4; ++g) acc[rs][g] = (float4v){0.f, 0.f, 0.f, 0.f};

#pragma unroll 2
  for (int k0 = 0; k0 < nk0; ++k0) {
    int kb = k0 * 32 + quad * 8;
    float a[RS][8];
#pragma unroll
    for (int rs = 0; rs < RS; ++rs) {
      if (xrow[rs] && kb + 8 <= K) {
        float4 v0 = *(const float4*)(xrow[rs] + kb);
        float4 v1 = *(const float4*)(xrow[rs] + kb + 4);
        a[rs][0] = v0.x; a[rs][1] = v0.y; a[rs][2] = v0.z; a[rs][3] = v0.w;
        a[rs][4] = v1.x; a[rs][5] = v1.y; a[rs][6] = v1.z; a[rs][7] = v1.w;
      } else {
#pragma unroll
        for (int j = 0; j < 8; ++j) {
          int k = kb + j;
          a[rs][j] = (xrow[rs] && k < K) ? xrow[rs][k] : 0.f;
        }
      }
    }
    short8 bf[4];
#pragma unroll
    for (int g = 0; g < 4; ++g) {
      if (PACKED) {
        bf[g] = *(const short8*)(Wpack + (((size_t)(g * nk0 + k0) * 64 + lane) << 3));
      } else {
        int n = g * 16 + m;
#pragma unroll
        for (int j = 0; j < 8; ++j) {
          int k = kb + j;
          float w = (k < K) ? Wf[(size_t)k * 64 + n] : 0.f;
          bf[g][j] = (short)f2bf(w);
        }
      }
    }
#pragma unroll
    for (int rs = 0; rs < RS; ++rs) {
      short8 af;
#pragma unroll
      for (int j = 0; j < 8; ++j) af[j] = (short)f2bf(a[rs][j]);
#pragma unroll
      for (int g = 0; g < 4; ++g)
        acc[rs][g] = __builtin_amdgcn_mfma_f32_16x16x32_bf16(af, bf[g], acc[rs][g], 0, 0, 0);
    }
  }

#pragma unroll
  for (int rs = 0; rs < RS; ++rs) {
    int rb = r0 + rs * 16;
    if (BF16PERM) {
      // lane m packs cols {m,16+m,32+m,48+m} of row rb+quad*4+j as 4 bf16 (8B)
      float b0 = bias ? bias[m] : 0.f;
      float b1 = bias ? bias[16 + m] : 0.f;
      float b2 = bias ? bias[32 + m] : 0.f;
      float b3 = bias ? bias[48 + m] : 0.f;
#pragma unroll
      for (int j = 0; j < 4; ++j) {
        int r = rb + quad * 4 + j;
        if (r < R) {
          ushort4 pk;
          pk.x = f2bf(acc[rs][0][j] + b0);
          pk.y = f2bf(acc[rs][1][j] + b1);
          pk.z = f2bf(acc[rs][2][j] + b2);
          pk.w = f2bf(acc[rs][3][j] + b3);
          *(ushort4*)((unsigned short*)outv + ((size_t)r * 64 + m * 4)) = pk;
        }
      }
    } else {
#pragma unroll
      for (int g = 0; g < 4; ++g) {
        float b = bias ? bias[g * 16 + m] : 0.f;
#pragma unroll
        for (int reg = 0; reg < 4; ++reg) {
          int r = rb + quad * 4 + reg;   // C/D: col=lane&15, row=quad*4+reg
          if (r < R) ((float*)outv)[(size_t)r * 64 + g * 16 + m] = acc[rs][g][reg] + b;
        }
      }
    }
  }
}

// k_pre: [fuseBlocks) fuse GEMM [Wlin;blin]@W1 -> WfuseB (strided fp32 B);
//        [+24) pack W1; [+2) pack W2 (permuted k);
//        rest: histogram -- cnt[dst]++ AND wdeg[dst]+=w (degrees before fill).
__global__ __launch_bounds__(256) void k_pre(
    const float* __restrict__ Wlin, const float* __restrict__ blin,
    const float* __restrict__ W1, float* __restrict__ WfuseB,
    unsigned short* __restrict__ packW1,
    const float* __restrict__ W2, unsigned short* __restrict__ packW2,
    int fuseBlocks,
    const int* __restrict__ ei, const float* __restrict__ ew, int E,
    int* __restrict__ cnt, float* __restrict__ wdeg) {
  int b = blockIdx.x;
  if (b < fuseBlocks) {
    mfma_gemm_body<true, false, false, 2>(Wlin, 768, blin, nullptr, W1, 24, 768,
                                          nullptr, WfuseB, 301, b * 4 + (threadIdx.x >> 6));
    return;
  }
  b -= fuseBlocks;
  if (b < 24) { pack_w_body<false>(W1, 768, 24, packW1, b * 256 + threadIdx.x); return; }
  b -= 24;
  if (b < 2) { pack_w_body<true>(W2, 64, 2, packW2, b * 256 + threadIdx.x); return; }
  b -= 2;
  int e0 = (b * 256 + threadIdx.x) * 4;
  if (e0 + 4 <= E && (E & 3) == 0) {
    int4 d4 = *(const int4*)(ei + E + e0);   // dst indices
    float4 w4 = *(const float4*)(ew + e0);
    atomicAdd(cnt + d4.x, 1); atomicAdd(wdeg + d4.x, w4.x);
    atomicAdd(cnt + d4.y, 1); atomicAdd(wdeg + d4.y, w4.y);
    atomicAdd(cnt + d4.z, 1); atomicAdd(wdeg + d4.z, w4.z);
    atomicAdd(cnt + d4.w, 1); atomicAdd(wdeg + d4.w, w4.w);
  } else {
#pragma unroll
    for (int j = 0; j < 4; ++j) {
      int e = e0 + j;
      if (e < E) {
        atomicAdd(cnt + ei[E + e], 1);
        atomicAdd(wdeg + ei[E + e], ew[e]);
      }
    }
  }
}

// ---- 3-kernel exclusive scan of (cnt[i]+1) -> offs[N+1] --------------------
// scan_reduce also hosts the packWf blocks (WfuseB ready after k_pre).
__global__ void k_scan_reduce(const int* __restrict__ cnt, int N, int* __restrict__ bsum,
                              int nbScan,
                              const float* __restrict__ WfuseB,
                              unsigned short* __restrict__ packWf) {
  if ((int)blockIdx.x >= nbScan) {
    pack_w_body<false>(WfuseB, 300, 10, packWf,
                       ((int)blockIdx.x - nbScan) * 256 + (int)threadIdx.x);
    return;
  }
  __shared__ int sd[256];
  int b = blockIdx.x, t = threadIdx.x;
  int base = b * 1024 + t * 4;
  int s = 0;
#pragma unroll
  for (int j = 0; j < 4; ++j) s += (base + j < N) ? cnt[base + j] + 1 : 0;
  sd[t] = s; __syncthreads();
  for (int off = 128; off > 0; off >>= 1) {
    if (t < off) sd[t] += sd[t + off];
    __syncthreads();
  }
  if (t == 0) bsum[b] = sd[0];
}

__global__ void k_scan_small(int* __restrict__ bsum, int nb) {
  __shared__ int s[128];
  int t = threadIdx.x;
  int v = (t < nb) ? bsum[t] : 0;
  s[t] = v; __syncthreads();
  for (int off = 1; off < 128; off <<= 1) {
    int x = (t >= off) ? s[t - off] : 0;
    __syncthreads();
    s[t] += x;
    __syncthreads();
  }
  if (t < nb) bsum[t] = s[t] - v;   // exclusive
}

// scan_final: offs, cursor, dis = rsqrt(1+wdeg), self-loop entry = dis^2.
__global__ void k_scan_final(const int* __restrict__ cnt, const float* __restrict__ wdeg,
                             int N, const int* __restrict__ bsum,
                             int* __restrict__ offs, int* __restrict__ cursor,
                             float* __restrict__ dis, int2* __restrict__ entries) {
  __shared__ int sd[256];
  int b = blockIdx.x, t = threadIdx.x;
  int base = b * 1024 + t * 4;
  int v[4], loc = 0;
#pragma unroll
  for (int j = 0; j < 4; ++j) { v[j] = (base + j < N) ? cnt[base + j] + 1 : 0; loc += v[j]; }
  sd[t] = loc; __syncthreads();
  for (int off = 1; off < 256; off <<= 1) {
    int x = (t >= off) ? sd[t - off] : 0;
    __syncthreads();
    sd[t] += x;
    __syncthreads();
  }
  int run = bsum[b] + sd[t] - loc;
#pragma unroll
  for (int j = 0; j < 4; ++j) {
    if (base + j < N) {
      int i = base + j;
      offs[i] = run;
      cursor[i] = run + 1;                         // slot 0 = self loop
      float ds = rsqrtf(fmaxf(1.f + wdeg[i], 1e-12f));
      dis[i] = ds;
      entries[run] = make_int2(i, __float_as_int(ds * ds));  // normalized self
      run += v[j];
    }
  }
  if (b == gridDim.x - 1 && t == 255) offs[N] = run;  // total = N + E
}

// k_main: [docBlocks) doc MFMA (packed W1); [+wordBlocks) word MFMA (packed
// WfuseB); rest: CSR FILL with final normalized weights dis[src]*w*dis[dst].
// Fill interleaves with the GEMM waves -> shared latency hiding.
__global__ __launch_bounds__(256) void k_main(
    const float* __restrict__ doc, const unsigned short* __restrict__ packW1,
    unsigned short* __restrict__ xw1, int ND, int docBlocks,
    const float* __restrict__ wordf, const unsigned short* __restrict__ packWf,
    const float* __restrict__ bfuse, unsigned short* __restrict__ xw1word,
    int NW, int wordBlocks,
    const int* __restrict__ ei, const float* __restrict__ ew, int E,
    int* __restrict__ cursor, const float* __restrict__ dis,
    int2* __restrict__ entries) {
  int b = blockIdx.x;
  if (b < docBlocks) {
    mfma_gemm_body<false, true, true, 2>(doc, 768, nullptr, packW1, nullptr, 24, 768,
                                         nullptr, xw1, ND, b * 4 + (threadIdx.x >> 6));
    return;
  }
  b -= docBlocks;
  if (b < wordBlocks) {
    mfma_gemm_body<false, true, true, 2>(wordf, 300, nullptr, packWf, nullptr, 10, 300,
                                         bfuse, xw1word, NW, b * 4 + (threadIdx.x >> 6));
    return;
  }
  b -= wordBlocks;
  int e0 = (b * 256 + threadIdx.x) * 4;
  int src[4], dst[4];
  float w[4];
  if (e0 + 4 <= E && (E & 3) == 0) {
    int4 s4 = *(const int4*)(ei + e0);
    int4 d4 = *(const int4*)(ei + E + e0);
    float4 w4 = *(const float4*)(ew + e0);
    src[0] = s4.x; src[1] = s4.y; src[2] = s4.z; src[3] = s4.w;
    dst[0] = d4.x; dst[1] = d4.y; dst[2] = d4.z; dst[3] = d4.w;
    w[0] = w4.x; w[1] = w4.y; w[2] = w4.z; w[3] = w4.w;
  } else {
#pragma unroll
    for (int j = 0; j < 4; ++j) {
      int e = e0 + j;
      if (e < E) { src[j] = ei[e]; dst[j] = ei[E + e]; w[j] = ew[e]; }
      else { src[j] = 0; dst[j] = 0; w[j] = 0.f; }
    }
  }
  float nrm[4];
#pragma unroll
  for (int j = 0; j < 4; ++j)
    if (e0 + j < E) nrm[j] = dis[src[j]] * w[j] * dis[dst[j]];
  int pos[4];
#pragma unroll
  for (int j = 0; j < 4; ++j)
    if (e0 + j < E) pos[j] = atomicAdd(cursor + dst[j], 1);
#pragma unroll
  for (int j = 0; j < 4; ++j)
    if (e0 + j < E) entries[pos[j]] = make_int2(src[j], __float_as_int(nrm[j]));
}

// half-wave gather-accumulate: 32 lanes, each lane covers 2 cols (ushort2).
__device__ __forceinline__ void row_gather2(const unsigned short* __restrict__ xin,
                                            const int2* __restrict__ entries,
                                            int p, int pe, int l32,
                                            float& ra0, float& ra1) {
  float a0 = 0.f, a1 = 0.f;
  for (; p + 8 <= pe; p += 8) {
    int2 e[8];
#pragma unroll
    for (int j = 0; j < 8; ++j) e[j] = entries[p + j];
    unsigned x[8];
#pragma unroll
    for (int j = 0; j < 8; ++j)
      x[j] = *(const unsigned*)(xin + ((size_t)e[j].x << 6) + (l32 << 1));
#pragma unroll
    for (int j = 0; j < 8; ++j) {
      float w = __int_as_float(e[j].y);
      a0 = fmaf(bf2f((unsigned short)(x[j] & 0xffffu)), w, a0);
      a1 = fmaf(bf2f((unsigned short)(x[j] >> 16)), w, a1);
    }
  }
  if (p + 4 <= pe) {
    int2 e[4];
#pragma unroll
    for (int j = 0; j < 4; ++j) e[j] = entries[p + j];
    unsigned x[4];
#pragma unroll
    for (int j = 0; j < 4; ++j)
      x[j] = *(const unsigned*)(xin + ((size_t)e[j].x << 6) + (l32 << 1));
#pragma unroll
    for (int j = 0; j < 4; ++j) {
      float w = __int_as_float(e[j].y);
      a0 = fmaf(bf2f((unsigned short)(x[j] & 0xffffu)), w, a0);
      a1 = fmaf(bf2f((unsigned short)(x[j] >> 16)), w, a1);
    }
    p += 4;
  }
  if (p + 2 <= pe) {
    int2 e0 = entries[p], e1 = entries[p + 1];
    unsigned x0 = *(const unsigned*)(xin + ((size_t)e0.x << 6) + (l32 << 1));
    unsigned x1 = *(const unsigned*)(xin + ((size_t)e1.x << 6) + (l32 << 1));
    float w0 = __int_as_float(e0.y), w1 = __int_as_float(e1.y);
    a0 = fmaf(bf2f((unsigned short)(x0 & 0xffffu)), w0, a0);
    a1 = fmaf(bf2f((unsigned short)(x0 >> 16)), w0, a1);
    a0 = fmaf(bf2f((unsigned short)(x1 & 0xffffu)), w1, a0);
    a1 = fmaf(bf2f((unsigned short)(x1 >> 16)), w1, a1);
    p += 2;
  }
  if (p < pe) {
    int2 e = entries[p];
    unsigned x = *(const unsigned*)(xin + ((size_t)e.x << 6) + (l32 << 1));
    float w = __int_as_float(e.y);
    a0 = fmaf(bf2f((unsigned short)(x & 0xffffu)), w, a0);
    a1 = fmaf(bf2f((unsigned short)(x >> 16)), w, a1);
  }
  ra0 = a0; ra1 = a1;
}

// layer-1 aggregation: half-wave per node, ushort2 out (permuted pos layout).
// entries hold FINAL normalized weights -> no dis multiply here.
__global__ void k_agg(const unsigned short* __restrict__ xin, const int2* __restrict__ entries,
                      const int* __restrict__ offs,
                      const float* __restrict__ bias, unsigned short* __restrict__ xout, int N) {
  const int tid = threadIdx.x;
  const int l32 = tid & 31;
  int i = blockIdx.x * 8 + (tid >> 5);
  if (i >= N) return;
  float a0, a1;
  row_gather2(xin, entries, offs[i], offs[i + 1], l32, a0, a1);
  a0 = fmaxf(a0 + bias[permcol(2 * l32)], 0.f);
  a1 = fmaxf(a1 + bias[permcol(2 * l32 + 1)], 0.f);
  ushort2 pk;
  pk.x = f2bf(a0);
  pk.y = f2bf(a1);
  *(ushort2*)(xout + ((size_t)i << 6) + (l32 << 1)) = pk;
}

// masked layer-2 aggregation: half-wave per masked node, fp32 out + y[mask]
__global__ void k_agg2m(const unsigned short* __restrict__ xin, const int2* __restrict__ entries,
                        const int* __restrict__ offs,
                        const int* __restrict__ mask, const int* __restrict__ y,
                        float* __restrict__ tout, float* __restrict__ outY, int M) {
  const int tid = threadIdx.x;
  const int l32 = tid & 31;
  int o = blockIdx.x * 8 + (tid >> 5);
  if (o >= M) return;
  int i = mask[o];
  float a0, a1;
  row_gather2(xin, entries, offs[i], offs[i + 1], l32, a0, a1);
  float2 pk;
  pk.x = a0;
  pk.y = a1;
  *(float2*)(tout + ((size_t)o << 6) + (l32 << 1)) = pk;
  if (l32 == 0) outY[o] = (float)y[i];
}

// final projection [M,64]@[64,64]+b2 via MFMA (permuted-k packed W2), fp32 out
__global__ __launch_bounds__(256) void k_mfma_final(
    const float* __restrict__ X, const unsigned short* __restrict__ packW2,
    const float* __restrict__ b2, float* __restrict__ out, int M) {
  mfma_gemm_body<false, true, false, 2>(X, 64, nullptr, packW2, nullptr, 2, 64,
                                        b2, out, M, blockIdx.x * 4 + (threadIdx.x >> 6));
}

extern "C" void kernel_launch(void* const* d_in, const int* in_sizes, int n_in,
                              void* d_out, int out_size, void* d_ws, size_t ws_size,
                              hipStream_t stream) {
  const float* doc   = (const float*)d_in[0];
  const float* wordf = (const float*)d_in[1];
  const float* ew    = (const float*)d_in[2];
  const float* Wlin  = (const float*)d_in[3];
  const float* blin  = (const float*)d_in[4];
  const float* W1    = (const float*)d_in[5];
  const float* b1    = (const float*)d_in[6];
  const float* W2    = (const float*)d_in[7];
  const float* b2    = (const float*)d_in[8];
  const int*   ei    = (const int*)d_in[9];
  const int*   mask  = (const int*)d_in[10];
  const int*   y     = (const int*)d_in[11];

  const int E  = in_sizes[2];
  const int M  = in_sizes[10];
  const int ND = in_sizes[0] / 768;
  const int NW = in_sizes[1] / 300;
  const int N  = ND + NW;
  const int NE = N + E;

  // workspace carve (aligned 256B)
  char* p = (char*)d_ws;
  auto carve = [&](size_t bytes) -> void* {
    void* q = (void*)p;
    p += (bytes + 255) & ~(size_t)255;
    return q;
  };
  float*          WfuseB = (float*)carve(301 * 64 * 4);
  unsigned short* packW1 = (unsigned short*)carve((size_t)4 * 24 * 64 * 8 * 2);
  unsigned short* packW2 = (unsigned short*)carve((size_t)4 * 2 * 64 * 8 * 2);
  unsigned short* packWf = (unsigned short*)carve((size_t)4 * 10 * 64 * 8 * 2);
  float* dis    = (float*)carve((size_t)N * 4);
  int*   cnt    = (int*)carve((size_t)2 * N * 4);   // cnt[N] + wdeg[N] (one memset)
  float* wdeg   = (float*)(cnt + N);
  int*   offs   = (int*)carve(((size_t)N + 1) * 4);
  int*   cursor = (int*)carve((size_t)N * 4);
  int*   bsum   = (int*)carve(1024);
  int2*  entries = (int2*)carve((size_t)NE * 8);
  unsigned short* xw1 = (unsigned short*)carve((size_t)N * 64 * 2);  // bf16, permuted cols
  unsigned short* h1  = (unsigned short*)carve((size_t)N * 64 * 2);  // bf16, permuted cols
  float* tmask = (float*)carve((size_t)M * 64 * 4);                  // fp32, permuted cols

  hipMemsetAsync(cnt, 0, (size_t)2 * N * 4, stream);   // zero cnt + wdeg

  // k_pre: fuse MFMA || pack W1 || pack W2 || histogram (cnt + wdeg)
  const int fuseBlocks = (301 + 127) / 128;   // RS=2: 32 rows/wave, 4 waves/blk
  const int cntBlocks  = (E + 1023) / 1024;
  k_pre<<<fuseBlocks + 24 + 2 + cntBlocks, 256, 0, stream>>>(
      Wlin, blin, W1, WfuseB, packW1, W2, packW2, fuseBlocks,
      ei, ew, E, cnt, wdeg);

  int nb = (N + 1023) / 1024;
  k_scan_reduce<<<nb + 10, 256, 0, stream>>>(cnt, N, bsum, nb, WfuseB, packWf);
  k_scan_small<<<1, 128, 0, stream>>>(bsum, nb);
  k_scan_final<<<nb, 256, 0, stream>>>(cnt, wdeg, N, bsum, offs, cursor, dis, entries);

  // k_main: doc MFMA || word MFMA || CSR fill (normalized entries)
  const int docBlocks  = (ND + 127) / 128;
  const int wordBlocks = (NW + 127) / 128;
  const int fillBlocks = (E + 1023) / 1024;
  k_main<<<docBlocks + wordBlocks + fillBlocks, 256, 0, stream>>>(
      doc, packW1, xw1, ND, docBlocks,
      wordf, packWf, WfuseB + (size_t)300 * 64, xw1 + (size_t)ND * 64, NW, wordBlocks,
      ei, ew, E, cursor, dis, entries);

  // layer-1 aggregation (+b1 via pi, relu) -> bf16 h1 (permuted)
  k_agg<<<(N + 7) / 8, 256, 0, stream>>>(xw1, entries, offs, b1, h1, N);

  // layer-2: masked aggregation over h1, then project [M,64]@[64,64]+b2
  float* out0 = (float*)d_out;
  float* outY = out0 + (size_t)M * 64;
  k_agg2m<<<(M + 7) / 8, 256, 0, stream>>>(h1, entries, offs, mask, y, tmask, outY, M);
  k_mfma_final<<<(M + 127) / 128, 256, 0, stream>>>(tmask, packW2, b2, out0, M);
}

// Round 4
// 357.887 us; speedup vs baseline: 1.2099x; 1.2099x over previous
//
#include <hip/hip_runtime.h>

// ---------------------------------------------------------------------------
// TextGCN (2-layer GCN, eval mode) on MI355X.
// Fusions:
//   * xw1_word = word @ (W_lin@W1) + (b_lin@W1)  (never materialize [N,768] x)
//   * layer 2: agg(h1@W2)[mask] == agg(h1)[mask] @ W2
// CSR BUILD = 2-LEVEL BUCKET SORT (no scattered-megaop atomics):
//   Measured (r3): each scattered 4-8B global atomic/write = 32B HBM sector
//   write-through at ~550 GB/s -> the old hist/fill cost ~126 MB of sector
//   traffic. Now: per-block LDS histograms over 391 coarse buckets (dst>>8),
//   ~96k run-reservation atomics total, dense run writes to ebuf, then one
//   block per bucket builds its CONTIGUOUS CSR slice (full-line writebacks),
//   computes offs/dis in LDS. Entries hold RAW w; agg multiplies dis[src]
//   (broadcast gather, 400KB L2-hot) and dis[dst] at the end.
// PIPELINE:
//   memset(1.6KB) -> k_pre(bucketHist || fuseGEMM || packW1 || packW2) ->
//   k_scanB(bucket scan || packWf) -> k_sd(scatter || docGEMM) ->
//   k_bw(bucketBuild || wordGEMM) -> k_agg -> k_agg2m -> k_mfma_final
// xw1/h1 bf16 in PERMUTED column order pi(pos)=(pos&3)*16+(pos>>2) (coalesced
// 8B MFMA epilogue stores). b1 indexed via pi; packW2 k-rows permuted via pi.
// MFMA GEMM: 32 rows/wave (2 rowsets SHARE each B-fragment load), no LDS.
// ebuf record: {src | (dst&255)<<17, w}  (src < 2^17 since N <= 131072).
// ---------------------------------------------------------------------------

typedef __attribute__((ext_vector_type(8))) short short8;   // 8 bf16 = 4 VGPR
typedef __attribute__((ext_vector_type(4))) float float4v;  // MFMA C/D frag

__device__ __forceinline__ unsigned short f2bf(float f) {   // RNE f32->bf16
  unsigned u = __float_as_uint(f);
  return (unsigned short)((u + 0x7FFFu + ((u >> 16) & 1u)) >> 16);
}
__device__ __forceinline__ float bf2f(unsigned short u) {
  return __uint_as_float((unsigned)u << 16);
}
__device__ __forceinline__ int permcol(int p) {   // pi: pos -> true col
  return ((p & 3) << 4) | (p >> 2);
}

// pack W[K,64] fp32 -> bf16 fragment order: pack[((g*nk0+k0)*64+lane)*8+j]
// holds W[ksrc][(lane&15)+16g], ksrc = PERM ? pi(k) : k; zero past K.
template <bool PERM>
__device__ __forceinline__ void pack_w_body(const float* __restrict__ W, int K,
                                            int nk0, unsigned short* __restrict__ pack,
                                            int tid) {
  int lane = tid & 63;
  int rest = tid >> 6;
  int k0 = rest % nk0;
  int g = rest / nk0;
  int quad = lane >> 4;
  int n = (lane & 15) + g * 16;
  short8 v;
#pragma unroll
  for (int j = 0; j < 8; ++j) {
    int k = k0 * 32 + quad * 8 + j;
    int ks = PERM ? permcol(k) : k;
    float w = (k < K) ? W[(size_t)ks * 64 + n] : 0.f;
    v[j] = (short)f2bf(w);
  }
  *(short8*)(pack + (((size_t)(g * nk0 + k0) * 64 + lane) << 3)) = v;
}

// MFMA GEMM: out[R,64] = X[R,K(ldx)] @ W[K,64] (+bias). One wave = 16*RS rows;
// RS rowsets share each B-fragment load (halves B traffic at RS=2).
template <bool LAST, bool PACKED, bool BF16PERM, int RS>
__device__ __forceinline__ void mfma_gemm_body(
    const float* __restrict__ X, int ldx, const float* __restrict__ lastRow,
    const unsigned short* __restrict__ Wpack, const float* __restrict__ Wf,
    int nk0, int K, const float* __restrict__ bias,
    void* __restrict__ outv, int R, int waveIdx) {
  int r0 = waveIdx * 16 * RS;
  if (r0 >= R) return;
  const int lane = threadIdx.x & 63;
  const int quad = lane >> 4;
  const int m = lane & 15;
  const float* xrow[RS];
#pragma unroll
  for (int rs = 0; rs < RS; ++rs) {
    int row = r0 + rs * 16 + m;
    xrow[rs] = nullptr;
    if (row < R) xrow[rs] = (LAST && row == R - 1) ? lastRow : X + (size_t)row * ldx;
  }

  float4v acc[RS][4];
#pragma unroll
  for (int rs = 0; rs < RS; ++rs)
#pragma unroll
    for (int g = 0; g < 4; ++g) acc[rs][g] = (float4v){0.f, 0.f, 0.f, 0.f};

#pragma unroll 2
  for (int k0 = 0; k0 < nk0; ++k0) {
    int kb = k0 * 32 + quad * 8;
    float a[RS][8];
#pragma unroll
    for (int rs = 0; rs < RS; ++rs) {
      if (xrow[rs] && kb + 8 <= K) {
        float4 v0 = *(const float4*)(xrow[rs] + kb);
        float4 v1 = *(const float4*)(xrow[rs] + kb + 4);
        a[rs][0] = v0.x; a[rs][1] = v0.y; a[rs][2] = v0.z; a[rs][3] = v0.w;
        a[rs][4] = v1.x; a[rs][5] = v1.y; a[rs][6] = v1.z; a[rs][7] = v1.w;
      } else {
#pragma unroll
        for (int j = 0; j < 8; ++j) {
          int k = kb + j;
          a[rs][j] = (xrow[rs] && k < K) ? xrow[rs][k] : 0.f;
        }
      }
    }
    short8 bf[4];
#pragma unroll
    for (int g = 0; g < 4; ++g) {
      if (PACKED) {
        bf[g] = *(const short8*)(Wpack + (((size_t)(g * nk0 + k0) * 64 + lane) << 3));
      } else {
        int n = g * 16 + m;
#pragma unroll
        for (int j = 0; j < 8; ++j) {
          int k = kb + j;
          float w = (k < K) ? Wf[(size_t)k * 64 + n] : 0.f;
          bf[g][j] = (short)f2bf(w);
        }
      }
    }
#pragma unroll
    for (int rs = 0; rs < RS; ++rs) {
      short8 af;
#pragma unroll
      for (int j = 0; j < 8; ++j) af[j] = (short)f2bf(a[rs][j]);
#pragma unroll
      for (int g = 0; g < 4; ++g)
        acc[rs][g] = __builtin_amdgcn_mfma_f32_16x16x32_bf16(af, bf[g], acc[rs][g], 0, 0, 0);
    }
  }

#pragma unroll
  for (int rs = 0; rs < RS; ++rs) {
    int rb = r0 + rs * 16;
    if (BF16PERM) {
      // lane m packs cols {m,16+m,32+m,48+m} of row rb+quad*4+j as 4 bf16 (8B)
      float b0 = bias ? bias[m] : 0.f;
      float b1 = bias ? bias[16 + m] : 0.f;
      float b2 = bias ? bias[32 + m] : 0.f;
      float b3 = bias ? bias[48 + m] : 0.f;
#pragma unroll
      for (int j = 0; j < 4; ++j) {
        int r = rb + quad * 4 + j;
        if (r < R) {
          ushort4 pk;
          pk.x = f2bf(acc[rs][0][j] + b0);
          pk.y = f2bf(acc[rs][1][j] + b1);
          pk.z = f2bf(acc[rs][2][j] + b2);
          pk.w = f2bf(acc[rs][3][j] + b3);
          *(ushort4*)((unsigned short*)outv + ((size_t)r * 64 + m * 4)) = pk;
        }
      }
    } else {
#pragma unroll
      for (int g = 0; g < 4; ++g) {
        float b = bias ? bias[g * 16 + m] : 0.f;
#pragma unroll
        for (int reg = 0; reg < 4; ++reg) {
          int r = rb + quad * 4 + reg;   // C/D: col=lane&15, row=quad*4+reg
          if (r < R) ((float*)outv)[(size_t)r * 64 + g * 16 + m] = acc[rs][g][reg] + b;
        }
      }
    }
  }
}

// k_pre: [histBlocks) bucket histogram (LDS, flush <=391 atomics/block);
//        [+fuseBlocks) fuse GEMM [Wlin;blin]@W1 -> WfuseB;
//        [+24) pack W1; [+2) pack W2 (permuted k).
__global__ __launch_bounds__(256) void k_pre(
    const float* __restrict__ Wlin, const float* __restrict__ blin,
    const float* __restrict__ W1, float* __restrict__ WfuseB,
    unsigned short* __restrict__ packW1,
    const float* __restrict__ W2, unsigned short* __restrict__ packW2,
    int histBlocks, int fuseBlocks,
    const int* __restrict__ ei, int E, int* __restrict__ bucketTot, int nbuck) {
  int b = blockIdx.x;
  int t = threadIdx.x;
  if (b < histBlocks) {
    __shared__ int h[512];
    h[t] = 0; h[t + 256] = 0;
    __syncthreads();
    int e0 = b * 4096;
#pragma unroll 4
    for (int i = 0; i < 16; ++i) {
      int e = e0 + t + i * 256;
      if (e < E) atomicAdd(&h[ei[E + e] >> 8], 1);
    }
    __syncthreads();
    if (t < nbuck && h[t]) atomicAdd(bucketTot + t, h[t]);
    if (t + 256 < nbuck && h[t + 256]) atomicAdd(bucketTot + t + 256, h[t + 256]);
    return;
  }
  b -= histBlocks;
  if (b < fuseBlocks) {
    mfma_gemm_body<true, false, false, 2>(Wlin, 768, blin, nullptr, W1, 24, 768,
                                          nullptr, WfuseB, 301, b * 4 + (t >> 6));
    return;
  }
  b -= fuseBlocks;
  if (b < 24) { pack_w_body<false>(W1, 768, 24, packW1, b * 256 + t); return; }
  b -= 24;
  pack_w_body<true>(W2, 64, 2, packW2, b * 256 + t);
}

// k_scanB: block 0 = exclusive scan of bucketTot -> bucketBase/bucketRun;
//          blocks 1..5 = pack WfuseB (rows 0..299) -> bf16 fragments.
__global__ __launch_bounds__(512) void k_scanB(
    const int* __restrict__ bucketTot, int nbuck,
    int* __restrict__ bucketBase, int* __restrict__ bucketRun,
    const float* __restrict__ WfuseB, unsigned short* __restrict__ packWf) {
  int t = threadIdx.x;
  if (blockIdx.x > 0) {
    pack_w_body<false>(WfuseB, 300, 10, packWf, ((int)blockIdx.x - 1) * 512 + t);
    return;
  }
  __shared__ int s[512];
  int v = (t < nbuck) ? bucketTot[t] : 0;
  s[t] = v; __syncthreads();
  for (int off = 1; off < 512; off <<= 1) {
    int x = (t >= off) ? s[t - off] : 0;
    __syncthreads();
    s[t] += x;
    __syncthreads();
  }
  if (t < nbuck) {
    int ex = s[t] - v;
    bucketBase[t] = ex;
    bucketRun[t] = ex;
  }
  if (t == nbuck - 1) bucketBase[nbuck] = s[t];   // = E
}

// k_sd: [scatBlocks) scatter edges into bucket-grouped ebuf (LDS ranks, one
// run-reservation atomic per non-empty (block,bucket)); rest: doc GEMM.
__global__ __launch_bounds__(256) void k_sd(
    const int* __restrict__ ei, const float* __restrict__ ew, int E,
    int scatBlocks, int* __restrict__ bucketRun, int2* __restrict__ ebuf,
    const float* __restrict__ doc, const unsigned short* __restrict__ packW1,
    unsigned short* __restrict__ xw1, int ND) {
  int b = blockIdx.x;
  int t = threadIdx.x;
  if (b >= scatBlocks) {
    mfma_gemm_body<false, true, true, 2>(doc, 768, nullptr, packW1, nullptr, 24, 768,
                                         nullptr, xw1, ND, (b - scatBlocks) * 4 + (t >> 6));
    return;
  }
  __shared__ int h[512];
  __shared__ int base[512];
  __shared__ int cur[512];
  h[t] = 0; h[t + 256] = 0;
  __syncthreads();
  int e0 = b * 4096;
#pragma unroll 4
  for (int i = 0; i < 16; ++i) {
    int e = e0 + t + i * 256;
    if (e < E) atomicAdd(&h[ei[E + e] >> 8], 1);
  }
  __syncthreads();
#pragma unroll
  for (int k = t; k < 512; k += 256) {
    if (h[k]) base[k] = atomicAdd(bucketRun + k, h[k]);
    cur[k] = 0;
  }
  __syncthreads();
#pragma unroll 4
  for (int i = 0; i < 16; ++i) {
    int e = e0 + t + i * 256;
    if (e < E) {
      int d = ei[E + e];
      int bk = d >> 8;
      int r = base[bk] + atomicAdd(&cur[bk], 1);
      ebuf[r] = make_int2(ei[e] | ((d & 255) << 17), __float_as_int(ew[e]));
    }
  }
}

// k_bw: [nbuck) per-bucket CSR build (LDS cnt/wdeg/scan -> contiguous
// entries slice + offs + dis); rest: word GEMM.
__global__ __launch_bounds__(256) void k_bw(
    const int2* __restrict__ ebuf, const int* __restrict__ bucketBase,
    int nbuck, int N, int* __restrict__ offs, float* __restrict__ dis,
    int2* __restrict__ entries,
    const float* __restrict__ wordf, const unsigned short* __restrict__ packWf,
    const float* __restrict__ bfuse, unsigned short* __restrict__ xw1word, int NW) {
  int b = blockIdx.x;
  int t = threadIdx.x;
  if (b >= nbuck) {
    mfma_gemm_body<false, true, true, 2>(wordf, 300, nullptr, packWf, nullptr, 10, 300,
                                         bfuse, xw1word, NW, (b - nbuck) * 4 + (t >> 6));
    return;
  }
  __shared__ int scnt[256];
  __shared__ float swd[256];
  __shared__ int sscan[256];
  __shared__ int scur[256];
  int node0 = b << 8;
  int nn = min(256, N - node0);
  int estart = bucketBase[b], eend = bucketBase[b + 1];
  scnt[t] = (t < nn) ? 1 : 0;          // self loop
  swd[t] = (t < nn) ? 1.f : 0.f;       // self weight
  __syncthreads();
  for (int p = estart + t; p < eend; p += 256) {
    int2 e = ebuf[p];
    int low = (e.x >> 17) & 255;
    atomicAdd(&scnt[low], 1);
    atomicAdd(&swd[low], __int_as_float(e.y));
  }
  __syncthreads();
  int v = scnt[t];
  sscan[t] = v; __syncthreads();
  for (int off = 1; off < 256; off <<= 1) {
    int x = (t >= off) ? sscan[t - off] : 0;
    __syncthreads();
    sscan[t] += x;
    __syncthreads();
  }
  int excl = sscan[t] - v;
  int entriesBase = estart + node0;    // edges-before + selfs-before
  if (t < nn) {
    offs[node0 + t] = entriesBase + excl;
    dis[node0 + t] = rsqrtf(fmaxf(swd[t], 1e-12f));
    entries[entriesBase + excl] = make_int2(node0 + t, __float_as_int(1.0f));
  }
  scur[t] = excl + 1;
  if (t == 0 && b == nbuck - 1) offs[N] = entriesBase + (eend - estart) + nn;
  __syncthreads();
  for (int p = estart + t; p < eend; p += 256) {
    int2 e = ebuf[p];
    int low = (e.x >> 17) & 255;
    int r = atomicAdd(&scur[low], 1);
    entries[entriesBase + r] = make_int2(e.x & 0x1FFFF, e.y);
  }
}

// half-wave gather-accumulate: 32 lanes, each lane covers 2 cols (ushort2).
// entries hold RAW w -> multiply dis[src] per entry (broadcast, L2-hot).
__device__ __forceinline__ void row_gather2(const unsigned short* __restrict__ xin,
                                            const int2* __restrict__ entries,
                                            const float* __restrict__ dis,
                                            int p, int pe, int l32,
                                            float& ra0, float& ra1) {
  float a0 = 0.f, a1 = 0.f;
  for (; p + 8 <= pe; p += 8) {
    int2 e[8];
#pragma unroll
    for (int j = 0; j < 8; ++j) e[j] = entries[p + j];
    unsigned x[8];
    float ds[8];
#pragma unroll
    for (int j = 0; j < 8; ++j) {
      x[j] = *(const unsigned*)(xin + ((size_t)e[j].x << 6) + (l32 << 1));
      ds[j] = dis[e[j].x];
    }
#pragma unroll
    for (int j = 0; j < 8; ++j) {
      float w = __int_as_float(e[j].y) * ds[j];
      a0 = fmaf(bf2f((unsigned short)(x[j] & 0xffffu)), w, a0);
      a1 = fmaf(bf2f((unsigned short)(x[j] >> 16)), w, a1);
    }
  }
  if (p + 4 <= pe) {
    int2 e[4];
#pragma unroll
    for (int j = 0; j < 4; ++j) e[j] = entries[p + j];
    unsigned x[4];
    float ds[4];
#pragma unroll
    for (int j = 0; j < 4; ++j) {
      x[j] = *(const unsigned*)(xin + ((size_t)e[j].x << 6) + (l32 << 1));
      ds[j] = dis[e[j].x];
    }
#pragma unroll
    for (int j = 0; j < 4; ++j) {
      float w = __int_as_float(e[j].y) * ds[j];
      a0 = fmaf(bf2f((unsigned short)(x[j] & 0xffffu)), w, a0);
      a1 = fmaf(bf2f((unsigned short)(x[j] >> 16)), w, a1);
    }
    p += 4;
  }
  for (; p < pe; ++p) {
    int2 e = entries[p];
    unsigned x = *(const unsigned*)(xin + ((size_t)e.x << 6) + (l32 << 1));
    float w = __int_as_float(e.y) * dis[e.x];
    a0 = fmaf(bf2f((unsigned short)(x & 0xffffu)), w, a0);
    a1 = fmaf(bf2f((unsigned short)(x >> 16)), w, a1);
  }
  ra0 = a0; ra1 = a1;
}

// layer-1 aggregation: half-wave per node, ushort2 out (permuted pos layout)
__global__ void k_agg(const unsigned short* __restrict__ xin, const int2* __restrict__ entries,
                      const int* __restrict__ offs, const float* __restrict__ dis,
                      const float* __restrict__ bias, unsigned short* __restrict__ xout, int N) {
  const int tid = threadIdx.x;
  const int l32 = tid & 31;
  int i = blockIdx.x * 8 + (tid >> 5);
  if (i >= N) return;
  float a0, a1;
  row_gather2(xin, entries, dis, offs[i], offs[i + 1], l32, a0, a1);
  float d = dis[i];
  a0 = fmaxf(fmaf(a0, d, bias[permcol(2 * l32)]), 0.f);
  a1 = fmaxf(fmaf(a1, d, bias[permcol(2 * l32 + 1)]), 0.f);
  ushort2 pk;
  pk.x = f2bf(a0);
  pk.y = f2bf(a1);
  *(ushort2*)(xout + ((size_t)i << 6) + (l32 << 1)) = pk;
}

// masked layer-2 aggregation: half-wave per masked node, fp32 out + y[mask]
__global__ void k_agg2m(const unsigned short* __restrict__ xin, const int2* __restrict__ entries,
                        const int* __restrict__ offs, const float* __restrict__ dis,
                        const int* __restrict__ mask, const int* __restrict__ y,
                        float* __restrict__ tout, float* __restrict__ outY, int M) {
  const int tid = threadIdx.x;
  const int l32 = tid & 31;
  int o = blockIdx.x * 8 + (tid >> 5);
  if (o >= M) return;
  int i = mask[o];
  float a0, a1;
  row_gather2(xin, entries, dis, offs[i], offs[i + 1], l32, a0, a1);
  float d = dis[i];
  float2 pk;
  pk.x = a0 * d;
  pk.y = a1 * d;
  *(float2*)(tout + ((size_t)o << 6) + (l32 << 1)) = pk;
  if (l32 == 0) outY[o] = (float)y[i];
}

// final projection [M,64]@[64,64]+b2 via MFMA (permuted-k packed W2), fp32 out
__global__ __launch_bounds__(256) void k_mfma_final(
    const float* __restrict__ X, const unsigned short* __restrict__ packW2,
    const float* __restrict__ b2, float* __restrict__ out, int M) {
  mfma_gemm_body<false, true, false, 2>(X, 64, nullptr, packW2, nullptr, 2, 64,
                                        b2, out, M, blockIdx.x * 4 + (threadIdx.x >> 6));
}

extern "C" void kernel_launch(void* const* d_in, const int* in_sizes, int n_in,
                              void* d_out, int out_size, void* d_ws, size_t ws_size,
                              hipStream_t stream) {
  const float* doc   = (const float*)d_in[0];
  const float* wordf = (const float*)d_in[1];
  const float* ew    = (const float*)d_in[2];
  const float* Wlin  = (const float*)d_in[3];
  const float* blin  = (const float*)d_in[4];
  const float* W1    = (const float*)d_in[5];
  const float* b1    = (const float*)d_in[6];
  const float* W2    = (const float*)d_in[7];
  const float* b2    = (const float*)d_in[8];
  const int*   ei    = (const int*)d_in[9];
  const int*   mask  = (const int*)d_in[10];
  const int*   y     = (const int*)d_in[11];

  const int E  = in_sizes[2];
  const int M  = in_sizes[10];
  const int ND = in_sizes[0] / 768;
  const int NW = in_sizes[1] / 300;
  const int N  = ND + NW;
  const int NE = N + E;
  const int nbuck = (N + 255) >> 8;          // <= 512 (N <= 131072)

  // workspace carve (aligned 256B)
  char* p = (char*)d_ws;
  auto carve = [&](size_t bytes) -> void* {
    void* q = (void*)p;
    p += (bytes + 255) & ~(size_t)255;
    return q;
  };
  float*          WfuseB = (float*)carve(301 * 64 * 4);
  unsigned short* packW1 = (unsigned short*)carve((size_t)4 * 24 * 64 * 8 * 2);
  unsigned short* packW2 = (unsigned short*)carve((size_t)4 * 2 * 64 * 8 * 2);
  unsigned short* packWf = (unsigned short*)carve((size_t)4 * 10 * 64 * 8 * 2);
  float* dis       = (float*)carve((size_t)N * 4);
  int*   offs      = (int*)carve(((size_t)N + 1) * 4);
  int*   bucketTot = (int*)carve((size_t)(nbuck + 2) * 4);
  int*   bucketBase= (int*)carve((size_t)(nbuck + 2) * 4);
  int*   bucketRun = (int*)carve((size_t)(nbuck + 2) * 4);
  int2*  ebuf      = (int2*)carve((size_t)E * 8);
  int2*  entries   = (int2*)carve((size_t)NE * 8);
  unsigned short* xw1 = (unsigned short*)carve((size_t)N * 64 * 2);  // bf16, permuted
  unsigned short* h1  = (unsigned short*)carve((size_t)N * 64 * 2);  // bf16, permuted
  float* tmask = (float*)carve((size_t)M * 64 * 4);                  // fp32, permuted

  hipMemsetAsync(bucketTot, 0, (size_t)nbuck * 4, stream);

  // k_pre: bucket hist || fuse MFMA || pack W1 || pack W2
  const int fuseBlocks = (301 + 127) / 128;
  const int histBlocks = (E + 4095) / 4096;
  k_pre<<<histBlocks + fuseBlocks + 24 + 2, 256, 0, stream>>>(
      Wlin, blin, W1, WfuseB, packW1, W2, packW2,
      histBlocks, fuseBlocks, ei, E, bucketTot, nbuck);

  // bucket scan || packWf  (block 0 scan; blocks 1..5 pack 2560 threads)
  k_scanB<<<6, 512, 0, stream>>>(bucketTot, nbuck, bucketBase, bucketRun,
                                 WfuseB, packWf);

  // scatter || doc GEMM
  const int docBlocks  = (ND + 127) / 128;
  k_sd<<<histBlocks + docBlocks, 256, 0, stream>>>(
      ei, ew, E, histBlocks, bucketRun, ebuf,
      doc, packW1, xw1, ND);

  // per-bucket CSR build || word GEMM
  const int wordBlocks = (NW + 127) / 128;
  k_bw<<<nbuck + wordBlocks, 256, 0, stream>>>(
      ebuf, bucketBase, nbuck, N, offs, dis, entries,
      wordf, packWf, WfuseB + (size_t)300 * 64, xw1 + (size_t)ND * 64, NW);

  // layer-1 aggregation (+b1 via pi, relu) -> bf16 h1 (permuted)
  k_agg<<<(N + 7) / 8, 256, 0, stream>>>(xw1, entries, offs, dis, b1, h1, N);

  // layer-2: masked aggregation over h1, then project [M,64]@[64,64]+b2
  float* out0 = (float*)d_out;
  float* outY = out0 + (size_t)M * 64;
  k_agg2m<<<(M + 7) / 8, 256, 0, stream>>>(h1, entries, offs, dis, mask, y, tmask, outY, M);
  k_mfma_final<<<(M + 127) / 128, 256, 0, stream>>>(tmask, packW2, b2, out0, M);
}

// Round 5
// 343.646 us; speedup vs baseline: 1.2600x; 1.0414x over previous
//
#include <hip/hip_runtime.h>

// ---------------------------------------------------------------------------
// TextGCN (2-layer GCN, eval mode) on MI355X.
// Fusions:
//   * xw1_word = word @ (W_lin@W1) + (b_lin@W1)  (never materialize [N,768] x)
//   * layer 2: agg(h1@W2)[mask] == agg(h1)[mask] @ W2
// CSR BUILD = 2-LEVEL BUCKET SORT (no scattered-megaop atomics):
//   Measured (r3): each scattered 4-8B global atomic/write = 32B HBM sector
//   write-through at ~550 GB/s -> the old hist/fill cost ~126 MB of sector
//   traffic. Now: per-block LDS histograms over 391 coarse buckets (dst>>8),
//   ~96k run-reservation atomics total, dense run writes to ebuf, then one
//   block per bucket builds its CONTIGUOUS CSR slice (full-line writebacks),
//   computes offs/dis in LDS. Entries hold RAW w; agg multiplies dis[src]
//   (broadcast gather, 400KB L2-hot) and dis[dst] at the end.
// GEMM OCCUPANCY (r4): at RS=2 (32 rows/wave) the word GEMM is only 2500
//   waves = 10/CU -> grid-capped occupancy 34% = the measured latency wall.
//   RS=1 (16 rows/wave) doubles wave count (word 5000, doc 1250); packed B
//   re-fetch doubles but is L2-resident (negligible).
// PIPELINE:
//   memset(1.6KB) -> k_pre(bucketHist || fuseGEMM || packW1 || packW2) ->
//   k_scanB(bucket scan || packWf) -> k_sd(scatter || docGEMM) ->
//   k_bw(bucketBuild || wordGEMM) -> k_agg -> k_agg2m -> k_mfma_final
// xw1/h1 bf16 in PERMUTED column order pi(pos)=(pos&3)*16+(pos>>2) (coalesced
// 8B MFMA epilogue stores). b1 indexed via pi; packW2 k-rows permuted via pi.
// ebuf record: {src | (dst&255)<<17, w}  (src < 2^17 since N <= 131072).
// ---------------------------------------------------------------------------

typedef __attribute__((ext_vector_type(8))) short short8;   // 8 bf16 = 4 VGPR
typedef __attribute__((ext_vector_type(4))) float float4v;  // MFMA C/D frag

__device__ __forceinline__ unsigned short f2bf(float f) {   // RNE f32->bf16
  unsigned u = __float_as_uint(f);
  return (unsigned short)((u + 0x7FFFu + ((u >> 16) & 1u)) >> 16);
}
__device__ __forceinline__ float bf2f(unsigned short u) {
  return __uint_as_float((unsigned)u << 16);
}
__device__ __forceinline__ int permcol(int p) {   // pi: pos -> true col
  return ((p & 3) << 4) | (p >> 2);
}

// pack W[K,64] fp32 -> bf16 fragment order: pack[((g*nk0+k0)*64+lane)*8+j]
// holds W[ksrc][(lane&15)+16g], ksrc = PERM ? pi(k) : k; zero past K.
template <bool PERM>
__device__ __forceinline__ void pack_w_body(const float* __restrict__ W, int K,
                                            int nk0, unsigned short* __restrict__ pack,
                                            int tid) {
  int lane = tid & 63;
  int rest = tid >> 6;
  int k0 = rest % nk0;
  int g = rest / nk0;
  int quad = lane >> 4;
  int n = (lane & 15) + g * 16;
  short8 v;
#pragma unroll
  for (int j = 0; j < 8; ++j) {
    int k = k0 * 32 + quad * 8 + j;
    int ks = PERM ? permcol(k) : k;
    float w = (k < K) ? W[(size_t)ks * 64 + n] : 0.f;
    v[j] = (short)f2bf(w);
  }
  *(short8*)(pack + (((size_t)(g * nk0 + k0) * 64 + lane) << 3)) = v;
}

// MFMA GEMM: out[R,64] = X[R,K(ldx)] @ W[K,64] (+bias). One wave = 16*RS rows.
// RS=1 now (occupancy: grid supplies 2x waves; B re-fetch is L2-hot).
template <bool LAST, bool PACKED, bool BF16PERM, int RS>
__device__ __forceinline__ void mfma_gemm_body(
    const float* __restrict__ X, int ldx, const float* __restrict__ lastRow,
    const unsigned short* __restrict__ Wpack, const float* __restrict__ Wf,
    int nk0, int K, const float* __restrict__ bias,
    void* __restrict__ outv, int R, int waveIdx) {
  int r0 = waveIdx * 16 * RS;
  if (r0 >= R) return;
  const int lane = threadIdx.x & 63;
  const int quad = lane >> 4;
  const int m = lane & 15;
  const float* xrow[RS];
#pragma unroll
  for (int rs = 0; rs < RS; ++rs) {
    int row = r0 + rs * 16 + m;
    xrow[rs] = nullptr;
    if (row < R) xrow[rs] = (LAST && row == R - 1) ? lastRow : X + (size_t)row * ldx;
  }

  float4v acc[RS][4];
#pragma unroll
  for (int rs = 0; rs < RS; ++rs)
#pragma unroll
    for (int g = 0; g < 4; ++g) acc[rs][g] = (float4v){0.f, 0.f, 0.f, 0.f};

#pragma unroll 2
  for (int k0 = 0; k0 < nk0; ++k0) {
    int kb = k0 * 32 + quad * 8;
    float a[RS][8];
#pragma unroll
    for (int rs = 0; rs < RS; ++rs) {
      if (xrow[rs] && kb + 8 <= K) {
        float4 v0 = *(const float4*)(xrow[rs] + kb);
        float4 v1 = *(const float4*)(xrow[rs] + kb + 4);
        a[rs][0] = v0.x; a[rs][1] = v0.y; a[rs][2] = v0.z; a[rs][3] = v0.w;
        a[rs][4] = v1.x; a[rs][5] = v1.y; a[rs][6] = v1.z; a[rs][7] = v1.w;
      } else {
#pragma unroll
        for (int j = 0; j < 8; ++j) {
          int k = kb + j;
          a[rs][j] = (xrow[rs] && k < K) ? xrow[rs][k] : 0.f;
        }
      }
    }
    short8 bf[4];
#pragma unroll
    for (int g = 0; g < 4; ++g) {
      if (PACKED) {
        bf[g] = *(const short8*)(Wpack + (((size_t)(g * nk0 + k0) * 64 + lane) << 3));
      } else {
        int n = g * 16 + m;
#pragma unroll
        for (int j = 0; j < 8; ++j) {
          int k = kb + j;
          float w = (k < K) ? Wf[(size_t)k * 64 + n] : 0.f;
          bf[g][j] = (short)f2bf(w);
        }
      }
    }
#pragma unroll
    for (int rs = 0; rs < RS; ++rs) {
      short8 af;
#pragma unroll
      for (int j = 0; j < 8; ++j) af[j] = (short)f2bf(a[rs][j]);
#pragma unroll
      for (int g = 0; g < 4; ++g)
        acc[rs][g] = __builtin_amdgcn_mfma_f32_16x16x32_bf16(af, bf[g], acc[rs][g], 0, 0, 0);
    }
  }

#pragma unroll
  for (int rs = 0; rs < RS; ++rs) {
    int rb = r0 + rs * 16;
    if (BF16PERM) {
      // lane m packs cols {m,16+m,32+m,48+m} of row rb+quad*4+j as 4 bf16 (8B)
      float b0 = bias ? bias[m] : 0.f;
      float b1 = bias ? bias[16 + m] : 0.f;
      float b2 = bias ? bias[32 + m] : 0.f;
      float b3 = bias ? bias[48 + m] : 0.f;
#pragma unroll
      for (int j = 0; j < 4; ++j) {
        int r = rb + quad * 4 + j;
        if (r < R) {
          ushort4 pk;
          pk.x = f2bf(acc[rs][0][j] + b0);
          pk.y = f2bf(acc[rs][1][j] + b1);
          pk.z = f2bf(acc[rs][2][j] + b2);
          pk.w = f2bf(acc[rs][3][j] + b3);
          *(ushort4*)((unsigned short*)outv + ((size_t)r * 64 + m * 4)) = pk;
        }
      }
    } else {
#pragma unroll
      for (int g = 0; g < 4; ++g) {
        float b = bias ? bias[g * 16 + m] : 0.f;
#pragma unroll
        for (int reg = 0; reg < 4; ++reg) {
          int r = rb + quad * 4 + reg;   // C/D: col=lane&15, row=quad*4+reg
          if (r < R) ((float*)outv)[(size_t)r * 64 + g * 16 + m] = acc[rs][g][reg] + b;
        }
      }
    }
  }
}

// k_pre: [histBlocks) bucket histogram (LDS, flush <=391 atomics/block);
//        [+fuseBlocks) fuse GEMM [Wlin;blin]@W1 -> WfuseB;
//        [+24) pack W1; [+2) pack W2 (permuted k).
__global__ __launch_bounds__(256) void k_pre(
    const float* __restrict__ Wlin, const float* __restrict__ blin,
    const float* __restrict__ W1, float* __restrict__ WfuseB,
    unsigned short* __restrict__ packW1,
    const float* __restrict__ W2, unsigned short* __restrict__ packW2,
    int histBlocks, int fuseBlocks,
    const int* __restrict__ ei, int E, int* __restrict__ bucketTot, int nbuck) {
  int b = blockIdx.x;
  int t = threadIdx.x;
  if (b < histBlocks) {
    __shared__ int h[512];
    h[t] = 0; h[t + 256] = 0;
    __syncthreads();
    int e0 = b * 4096;
#pragma unroll 4
    for (int i = 0; i < 16; ++i) {
      int e = e0 + t + i * 256;
      if (e < E) atomicAdd(&h[ei[E + e] >> 8], 1);
    }
    __syncthreads();
    if (t < nbuck && h[t]) atomicAdd(bucketTot + t, h[t]);
    if (t + 256 < nbuck && h[t + 256]) atomicAdd(bucketTot + t + 256, h[t + 256]);
    return;
  }
  b -= histBlocks;
  if (b < fuseBlocks) {
    mfma_gemm_body<true, false, false, 1>(Wlin, 768, blin, nullptr, W1, 24, 768,
                                          nullptr, WfuseB, 301, b * 4 + (t >> 6));
    return;
  }
  b -= fuseBlocks;
  if (b < 24) { pack_w_body<false>(W1, 768, 24, packW1, b * 256 + t); return; }
  b -= 24;
  pack_w_body<true>(W2, 64, 2, packW2, b * 256 + t);
}

// k_scanB: block 0 = exclusive scan of bucketTot -> bucketBase/bucketRun;
//          blocks 1..5 = pack WfuseB (rows 0..299) -> bf16 fragments.
__global__ __launch_bounds__(512) void k_scanB(
    const int* __restrict__ bucketTot, int nbuck,
    int* __restrict__ bucketBase, int* __restrict__ bucketRun,
    const float* __restrict__ WfuseB, unsigned short* __restrict__ packWf) {
  int t = threadIdx.x;
  if (blockIdx.x > 0) {
    pack_w_body<false>(WfuseB, 300, 10, packWf, ((int)blockIdx.x - 1) * 512 + t);
    return;
  }
  __shared__ int s[512];
  int v = (t < nbuck) ? bucketTot[t] : 0;
  s[t] = v; __syncthreads();
  for (int off = 1; off < 512; off <<= 1) {
    int x = (t >= off) ? s[t - off] : 0;
    __syncthreads();
    s[t] += x;
    __syncthreads();
  }
  if (t < nbuck) {
    int ex = s[t] - v;
    bucketBase[t] = ex;
    bucketRun[t] = ex;
  }
  if (t == nbuck - 1) bucketBase[nbuck] = s[t];   // = E
}

// k_sd: [scatBlocks) scatter edges into bucket-grouped ebuf (LDS ranks, one
// run-reservation atomic per non-empty (block,bucket)); rest: doc GEMM.
__global__ __launch_bounds__(256) void k_sd(
    const int* __restrict__ ei, const float* __restrict__ ew, int E,
    int scatBlocks, int* __restrict__ bucketRun, int2* __restrict__ ebuf,
    const float* __restrict__ doc, const unsigned short* __restrict__ packW1,
    unsigned short* __restrict__ xw1, int ND) {
  int b = blockIdx.x;
  int t = threadIdx.x;
  if (b >= scatBlocks) {
    mfma_gemm_body<false, true, true, 1>(doc, 768, nullptr, packW1, nullptr, 24, 768,
                                         nullptr, xw1, ND, (b - scatBlocks) * 4 + (t >> 6));
    return;
  }
  __shared__ int h[512];
  __shared__ int base[512];
  __shared__ int cur[512];
  h[t] = 0; h[t + 256] = 0;
  __syncthreads();
  int e0 = b * 4096;
#pragma unroll 4
  for (int i = 0; i < 16; ++i) {
    int e = e0 + t + i * 256;
    if (e < E) atomicAdd(&h[ei[E + e] >> 8], 1);
  }
  __syncthreads();
#pragma unroll
  for (int k = t; k < 512; k += 256) {
    if (h[k]) base[k] = atomicAdd(bucketRun + k, h[k]);
    cur[k] = 0;
  }
  __syncthreads();
#pragma unroll 4
  for (int i = 0; i < 16; ++i) {
    int e = e0 + t + i * 256;
    if (e < E) {
      int d = ei[E + e];
      int bk = d >> 8;
      int r = base[bk] + atomicAdd(&cur[bk], 1);
      ebuf[r] = make_int2(ei[e] | ((d & 255) << 17), __float_as_int(ew[e]));
    }
  }
}

// k_bw: [nbuck) per-bucket CSR build (LDS cnt/wdeg/scan -> contiguous
// entries slice + offs + dis); rest: word GEMM.
__global__ __launch_bounds__(256) void k_bw(
    const int2* __restrict__ ebuf, const int* __restrict__ bucketBase,
    int nbuck, int N, int* __restrict__ offs, float* __restrict__ dis,
    int2* __restrict__ entries,
    const float* __restrict__ wordf, const unsigned short* __restrict__ packWf,
    const float* __restrict__ bfuse, unsigned short* __restrict__ xw1word, int NW) {
  int b = blockIdx.x;
  int t = threadIdx.x;
  if (b >= nbuck) {
    mfma_gemm_body<false, true, true, 1>(wordf, 300, nullptr, packWf, nullptr, 10, 300,
                                         bfuse, xw1word, NW, (b - nbuck) * 4 + (t >> 6));
    return;
  }
  __shared__ int scnt[256];
  __shared__ float swd[256];
  __shared__ int sscan[256];
  __shared__ int scur[256];
  int node0 = b << 8;
  int nn = min(256, N - node0);
  int estart = bucketBase[b], eend = bucketBase[b + 1];
  scnt[t] = (t < nn) ? 1 : 0;          // self loop
  swd[t] = (t < nn) ? 1.f : 0.f;       // self weight
  __syncthreads();
  for (int p = estart + t; p < eend; p += 256) {
    int2 e = ebuf[p];
    int low = (e.x >> 17) & 255;
    atomicAdd(&scnt[low], 1);
    atomicAdd(&swd[low], __int_as_float(e.y));
  }
  __syncthreads();
  int v = scnt[t];
  sscan[t] = v; __syncthreads();
  for (int off = 1; off < 256; off <<= 1) {
    int x = (t >= off) ? sscan[t - off] : 0;
    __syncthreads();
    sscan[t] += x;
    __syncthreads();
  }
  int excl = sscan[t] - v;
  int entriesBase = estart + node0;    // edges-before + selfs-before
  if (t < nn) {
    offs[node0 + t] = entriesBase + excl;
    dis[node0 + t] = rsqrtf(fmaxf(swd[t], 1e-12f));
    entries[entriesBase + excl] = make_int2(node0 + t, __float_as_int(1.0f));
  }
  scur[t] = excl + 1;
  if (t == 0 && b == nbuck - 1) offs[N] = entriesBase + (eend - estart) + nn;
  __syncthreads();
  for (int p = estart + t; p < eend; p += 256) {
    int2 e = ebuf[p];
    int low = (e.x >> 17) & 255;
    int r = atomicAdd(&scur[low], 1);
    entries[entriesBase + r] = make_int2(e.x & 0x1FFFF, e.y);
  }
}

// half-wave gather-accumulate: 32 lanes, each lane covers 2 cols (ushort2).
// entries hold RAW w -> multiply dis[src] per entry (broadcast, L2-hot).
__device__ __forceinline__ void row_gather2(const unsigned short* __restrict__ xin,
                                            const int2* __restrict__ entries,
                                            const float* __restrict__ dis,
                                            int p, int pe, int l32,
                                            float& ra0, float& ra1) {
  float a0 = 0.f, a1 = 0.f;
  for (; p + 8 <= pe; p += 8) {
    int2 e[8];
#pragma unroll
    for (int j = 0; j < 8; ++j) e[j] = entries[p + j];
    unsigned x[8];
    float ds[8];
#pragma unroll
    for (int j = 0; j < 8; ++j) {
      x[j] = *(const unsigned*)(xin + ((size_t)e[j].x << 6) + (l32 << 1));
      ds[j] = dis[e[j].x];
    }
#pragma unroll
    for (int j = 0; j < 8; ++j) {
      float w = __int_as_float(e[j].y) * ds[j];
      a0 = fmaf(bf2f((unsigned short)(x[j] & 0xffffu)), w, a0);
      a1 = fmaf(bf2f((unsigned short)(x[j] >> 16)), w, a1);
    }
  }
  if (p + 4 <= pe) {
    int2 e[4];
#pragma unroll
    for (int j = 0; j < 4; ++j) e[j] = entries[p + j];
    unsigned x[4];
    float ds[4];
#pragma unroll
    for (int j = 0; j < 4; ++j) {
      x[j] = *(const unsigned*)(xin + ((size_t)e[j].x << 6) + (l32 << 1));
      ds[j] = dis[e[j].x];
    }
#pragma unroll
    for (int j = 0; j < 4; ++j) {
      float w = __int_as_float(e[j].y) * ds[j];
      a0 = fmaf(bf2f((unsigned short)(x[j] & 0xffffu)), w, a0);
      a1 = fmaf(bf2f((unsigned short)(x[j] >> 16)), w, a1);
    }
    p += 4;
  }
  for (; p < pe; ++p) {
    int2 e = entries[p];
    unsigned x = *(const unsigned*)(xin + ((size_t)e.x << 6) + (l32 << 1));
    float w = __int_as_float(e.y) * dis[e.x];
    a0 = fmaf(bf2f((unsigned short)(x & 0xffffu)), w, a0);
    a1 = fmaf(bf2f((unsigned short)(x >> 16)), w, a1);
  }
  ra0 = a0; ra1 = a1;
}

// layer-1 aggregation: half-wave per node, ushort2 out (permuted pos layout)
__global__ void k_agg(const unsigned short* __restrict__ xin, const int2* __restrict__ entries,
                      const int* __restrict__ offs, const float* __restrict__ dis,
                      const float* __restrict__ bias, unsigned short* __restrict__ xout, int N) {
  const int tid = threadIdx.x;
  const int l32 = tid & 31;
  int i = blockIdx.x * 8 + (tid >> 5);
  if (i >= N) return;
  float a0, a1;
  row_gather2(xin, entries, dis, offs[i], offs[i + 1], l32, a0, a1);
  float d = dis[i];
  a0 = fmaxf(fmaf(a0, d, bias[permcol(2 * l32)]), 0.f);
  a1 = fmaxf(fmaf(a1, d, bias[permcol(2 * l32 + 1)]), 0.f);
  ushort2 pk;
  pk.x = f2bf(a0);
  pk.y = f2bf(a1);
  *(ushort2*)(xout + ((size_t)i << 6) + (l32 << 1)) = pk;
}

// masked layer-2 aggregation: half-wave per masked node, fp32 out + y[mask]
__global__ void k_agg2m(const unsigned short* __restrict__ xin, const int2* __restrict__ entries,
                        const int* __restrict__ offs, const float* __restrict__ dis,
                        const int* __restrict__ mask, const int* __restrict__ y,
                        float* __restrict__ tout, float* __restrict__ outY, int M) {
  const int tid = threadIdx.x;
  const int l32 = tid & 31;
  int o = blockIdx.x * 8 + (tid >> 5);
  if (o >= M) return;
  int i = mask[o];
  float a0, a1;
  row_gather2(xin, entries, dis, offs[i], offs[i + 1], l32, a0, a1);
  float d = dis[i];
  float2 pk;
  pk.x = a0 * d;
  pk.y = a1 * d;
  *(float2*)(tout + ((size_t)o << 6) + (l32 << 1)) = pk;
  if (l32 == 0) outY[o] = (float)y[i];
}

// final projection [M,64]@[64,64]+b2 via MFMA (permuted-k packed W2), fp32 out
__global__ __launch_bounds__(256) void k_mfma_final(
    const float* __restrict__ X, const unsigned short* __restrict__ packW2,
    const float* __restrict__ b2, float* __restrict__ out, int M) {
  mfma_gemm_body<false, true, false, 1>(X, 64, nullptr, packW2, nullptr, 2, 64,
                                        b2, out, M, blockIdx.x * 4 + (threadIdx.x >> 6));
}

extern "C" void kernel_launch(void* const* d_in, const int* in_sizes, int n_in,
                              void* d_out, int out_size, void* d_ws, size_t ws_size,
                              hipStream_t stream) {
  const float* doc   = (const float*)d_in[0];
  const float* wordf = (const float*)d_in[1];
  const float* ew    = (const float*)d_in[2];
  const float* Wlin  = (const float*)d_in[3];
  const float* blin  = (const float*)d_in[4];
  const float* W1    = (const float*)d_in[5];
  const float* b1    = (const float*)d_in[6];
  const float* W2    = (const float*)d_in[7];
  const float* b2    = (const float*)d_in[8];
  const int*   ei    = (const int*)d_in[9];
  const int*   mask  = (const int*)d_in[10];
  const int*   y     = (const int*)d_in[11];

  const int E  = in_sizes[2];
  const int M  = in_sizes[10];
  const int ND = in_sizes[0] / 768;
  const int NW = in_sizes[1] / 300;
  const int N  = ND + NW;
  const int NE = N + E;
  const int nbuck = (N + 255) >> 8;          // <= 512 (N <= 131072)

  // workspace carve (aligned 256B)
  char* p = (char*)d_ws;
  auto carve = [&](size_t bytes) -> void* {
    void* q = (void*)p;
    p += (bytes + 255) & ~(size_t)255;
    return q;
  };
  float*          WfuseB = (float*)carve(301 * 64 * 4);
  unsigned short* packW1 = (unsigned short*)carve((size_t)4 * 24 * 64 * 8 * 2);
  unsigned short* packW2 = (unsigned short*)carve((size_t)4 * 2 * 64 * 8 * 2);
  unsigned short* packWf = (unsigned short*)carve((size_t)4 * 10 * 64 * 8 * 2);
  float* dis       = (float*)carve((size_t)N * 4);
  int*   offs      = (int*)carve(((size_t)N + 1) * 4);
  int*   bucketTot = (int*)carve((size_t)(nbuck + 2) * 4);
  int*   bucketBase= (int*)carve((size_t)(nbuck + 2) * 4);
  int*   bucketRun = (int*)carve((size_t)(nbuck + 2) * 4);
  int2*  ebuf      = (int2*)carve((size_t)E * 8);
  int2*  entries   = (int2*)carve((size_t)NE * 8);
  unsigned short* xw1 = (unsigned short*)carve((size_t)N * 64 * 2);  // bf16, permuted
  unsigned short* h1  = (unsigned short*)carve((size_t)N * 64 * 2);  // bf16, permuted
  float* tmask = (float*)carve((size_t)M * 64 * 4);                  // fp32, permuted

  hipMemsetAsync(bucketTot, 0, (size_t)nbuck * 4, stream);

  // k_pre: bucket hist || fuse MFMA || pack W1 || pack W2
  const int fuseBlocks = (301 + 63) / 64;    // RS=1: 16 rows/wave
  const int histBlocks = (E + 4095) / 4096;
  k_pre<<<histBlocks + fuseBlocks + 24 + 2, 256, 0, stream>>>(
      Wlin, blin, W1, WfuseB, packW1, W2, packW2,
      histBlocks, fuseBlocks, ei, E, bucketTot, nbuck);

  // bucket scan || packWf  (block 0 scan; blocks 1..5 pack 2560 threads)
  k_scanB<<<6, 512, 0, stream>>>(bucketTot, nbuck, bucketBase, bucketRun,
                                 WfuseB, packWf);

  // scatter || doc GEMM
  const int docBlocks  = (ND + 63) / 64;     // RS=1
  k_sd<<<histBlocks + docBlocks, 256, 0, stream>>>(
      ei, ew, E, histBlocks, bucketRun, ebuf,
      doc, packW1, xw1, ND);

  // per-bucket CSR build || word GEMM
  const int wordBlocks = (NW + 63) / 64;     // RS=1: 5000 waves (~20/CU)
  k_bw<<<nbuck + wordBlocks, 256, 0, stream>>>(
      ebuf, bucketBase, nbuck, N, offs, dis, entries,
      wordf, packWf, WfuseB + (size_t)300 * 64, xw1 + (size_t)ND * 64, NW);

  // layer-1 aggregation (+b1 via pi, relu) -> bf16 h1 (permuted)
  k_agg<<<(N + 7) / 8, 256, 0, stream>>>(xw1, entries, offs, dis, b1, h1, N);

  // layer-2: masked aggregation over h1, then project [M,64]@[64,64]+b2
  float* out0 = (float*)d_out;
  float* outY = out0 + (size_t)M * 64;
  k_agg2m<<<(M + 7) / 8, 256, 0, stream>>>(h1, entries, offs, dis, mask, y, tmask, outY, M);
  k_mfma_final<<<(M + 63) / 64, 256, 0, stream>>>(tmask, packW2, b2, out0, M);
}

// Round 6
// 338.779 us; speedup vs baseline: 1.2781x; 1.0144x over previous
//
#include <hip/hip_runtime.h>

// ---------------------------------------------------------------------------
// TextGCN (2-layer GCN, eval mode) on MI355X.
// Fusions:
//   * xw1_word = word @ (W_lin@W1) + (b_lin@W1)  (never materialize [N,768] x)
//   * layer 2: agg(h1@W2)[mask] == agg(h1)[mask] @ W2
// CSR BUILD = 2-LEVEL BUCKET SORT (no scattered-megaop atomics):
//   r3 measured: scattered 4-8B atomics/writes cost 32B HBM sectors at
//   ~550 GB/s. LDS bucket histograms (dst>>8), dense run writes to ebuf,
//   per-bucket contiguous CSR build. Entries hold RAW w; agg multiplies
//   dis[src] (L2-hot) and dis[dst] at the end.
// GEMM MLP (r5): occupancy 34->55% left BW flat at 1.55 TB/s -> limit is
//   per-wave dependency structure. The A-access is a 16-row gather (stride
//   1200B); with unroll-2 each wave stalls on HBM 5-12x with only 64B/lane
//   outstanding. Fix: compile-time NK0 + CHUNK-deep A-load hoist -- issue
//   all CHUNK k0 A-loads back-to-back, then convert+MFMA. Word: 2 stalls
//   @160B/lane; doc: 3 stalls @256B/lane. VGPR stays <=128 (16 waves/CU).
// PIPELINE:
//   memset(1.6KB) -> k_pre(bucketHist || fuseGEMM || packW1 || packW2) ->
//   k_scanB(bucket scan || packWf) -> k_sd(scatter || docGEMM) ->
//   k_bw(bucketBuild || wordGEMM) -> k_agg -> k_agg2m -> k_mfma_final
// xw1/h1 bf16 in PERMUTED column order pi(pos)=(pos&3)*16+(pos>>2) (coalesced
// 8B MFMA epilogue stores). b1 indexed via pi; packW2 k-rows permuted via pi.
// ebuf record: {src | (dst&255)<<17, w}  (src < 2^17 since N <= 131072).
// ---------------------------------------------------------------------------

typedef __attribute__((ext_vector_type(8))) short short8;   // 8 bf16 = 4 VGPR
typedef __attribute__((ext_vector_type(4))) float float4v;  // MFMA C/D frag

__device__ __forceinline__ unsigned short f2bf(float f) {   // RNE f32->bf16
  unsigned u = __float_as_uint(f);
  return (unsigned short)((u + 0x7FFFu + ((u >> 16) & 1u)) >> 16);
}
__device__ __forceinline__ float bf2f(unsigned short u) {
  return __uint_as_float((unsigned)u << 16);
}
__device__ __forceinline__ int permcol(int p) {   // pi: pos -> true col
  return ((p & 3) << 4) | (p >> 2);
}

// pack W[K,64] fp32 -> bf16 fragment order: pack[((g*nk0+k0)*64+lane)*8+j]
// holds W[ksrc][(lane&15)+16g], ksrc = PERM ? pi(k) : k; zero past K.
template <bool PERM>
__device__ __forceinline__ void pack_w_body(const float* __restrict__ W, int K,
                                            int nk0, unsigned short* __restrict__ pack,
                                            int tid) {
  int lane = tid & 63;
  int rest = tid >> 6;
  int k0 = rest % nk0;
  int g = rest / nk0;
  int quad = lane >> 4;
  int n = (lane & 15) + g * 16;
  short8 v;
#pragma unroll
  for (int j = 0; j < 8; ++j) {
    int k = k0 * 32 + quad * 8 + j;
    int ks = PERM ? permcol(k) : k;
    float w = (k < K) ? W[(size_t)ks * 64 + n] : 0.f;
    v[j] = (short)f2bf(w);
  }
  *(short8*)(pack + (((size_t)(g * nk0 + k0) * 64 + lane) << 3)) = v;
}

// MFMA GEMM: out[R,64] = X[R,K(ldx)] @ W[K,64] (+bias). One wave = 16 rows.
// NK0/CHUNK compile-time: A-loads for CHUNK k0s issued back-to-back (deep
// MLP, few stalls/wave), then the chunk's convert+MFMA. a[][] fully unrolled
// -> stays in VGPRs (<=128 total, 16 waves/CU tier).
template <bool LAST, bool PACKED, bool BF16PERM, int NK0, int CHUNK>
__device__ __forceinline__ void mfma_gemm_body(
    const float* __restrict__ X, int ldx, const float* __restrict__ lastRow,
    const unsigned short* __restrict__ Wpack, const float* __restrict__ Wf,
    int K, const float* __restrict__ bias,
    void* __restrict__ outv, int R, int waveIdx) {
  int r0 = waveIdx * 16;
  if (r0 >= R) return;
  const int lane = threadIdx.x & 63;
  const int quad = lane >> 4;
  const int m = lane & 15;
  const float* xrow = nullptr;
  {
    int row = r0 + m;
    if (row < R) xrow = (LAST && row == R - 1) ? lastRow : X + (size_t)row * ldx;
  }

  float4v acc[4];
#pragma unroll
  for (int g = 0; g < 4; ++g) acc[g] = (float4v){0.f, 0.f, 0.f, 0.f};

#pragma unroll
  for (int c0 = 0; c0 < NK0; c0 += CHUNK) {
    // ---- A-hoist: all CHUNK k0 loads, no dependent compute between ----
    float a[CHUNK][8];
#pragma unroll
    for (int cc = 0; cc < CHUNK; ++cc) {
      int kb = (c0 + cc) * 32 + quad * 8;
      if (xrow && kb + 8 <= K) {
        float4 v0 = *(const float4*)(xrow + kb);
        float4 v1 = *(const float4*)(xrow + kb + 4);
        a[cc][0] = v0.x; a[cc][1] = v0.y; a[cc][2] = v0.z; a[cc][3] = v0.w;
        a[cc][4] = v1.x; a[cc][5] = v1.y; a[cc][6] = v1.z; a[cc][7] = v1.w;
      } else {
#pragma unroll
        for (int j = 0; j < 8; ++j) {
          int k = kb + j;
          a[cc][j] = (xrow && k < K) ? xrow[k] : 0.f;
        }
      }
    }
    // ---- compute the chunk ----
#pragma unroll
    for (int cc = 0; cc < CHUNK; ++cc) {
      int k0 = c0 + cc;
      short8 bf[4];
#pragma unroll
      for (int g = 0; g < 4; ++g) {
        if (PACKED) {
          bf[g] = *(const short8*)(Wpack + (((size_t)(g * NK0 + k0) * 64 + lane) << 3));
        } else {
          int n = g * 16 + m;
          int kb = k0 * 32 + quad * 8;
#pragma unroll
          for (int j = 0; j < 8; ++j) {
            int k = kb + j;
            float w = (k < K) ? Wf[(size_t)k * 64 + n] : 0.f;
            bf[g][j] = (short)f2bf(w);
          }
        }
      }
      short8 af;
#pragma unroll
      for (int j = 0; j < 8; ++j) af[j] = (short)f2bf(a[cc][j]);
#pragma unroll
      for (int g = 0; g < 4; ++g)
        acc[g] = __builtin_amdgcn_mfma_f32_16x16x32_bf16(af, bf[g], acc[g], 0, 0, 0);
    }
  }

  // ---- epilogue ----
  if (BF16PERM) {
    // lane m packs cols {m,16+m,32+m,48+m} of row r0+quad*4+j as 4 bf16 (8B)
    float b0 = bias ? bias[m] : 0.f;
    float b1 = bias ? bias[16 + m] : 0.f;
    float b2 = bias ? bias[32 + m] : 0.f;
    float b3 = bias ? bias[48 + m] : 0.f;
#pragma unroll
    for (int j = 0; j < 4; ++j) {
      int r = r0 + quad * 4 + j;
      if (r < R) {
        ushort4 pk;
        pk.x = f2bf(acc[0][j] + b0);
        pk.y = f2bf(acc[1][j] + b1);
        pk.z = f2bf(acc[2][j] + b2);
        pk.w = f2bf(acc[3][j] + b3);
        *(ushort4*)((unsigned short*)outv + ((size_t)r * 64 + m * 4)) = pk;
      }
    }
  } else {
#pragma unroll
    for (int g = 0; g < 4; ++g) {
      float b = bias ? bias[g * 16 + m] : 0.f;
#pragma unroll
      for (int reg = 0; reg < 4; ++reg) {
        int r = r0 + quad * 4 + reg;   // C/D: col=lane&15, row=quad*4+reg
        if (r < R) ((float*)outv)[(size_t)r * 64 + g * 16 + m] = acc[g][reg] + b;
      }
    }
  }
}

// k_pre: [histBlocks) bucket histogram (LDS, flush <=391 atomics/block);
//        [+fuseBlocks) fuse GEMM [Wlin;blin]@W1 -> WfuseB;
//        [+24) pack W1; [+2) pack W2 (permuted k).
__global__ __launch_bounds__(256) void k_pre(
    const float* __restrict__ Wlin, const float* __restrict__ blin,
    const float* __restrict__ W1, float* __restrict__ WfuseB,
    unsigned short* __restrict__ packW1,
    const float* __restrict__ W2, unsigned short* __restrict__ packW2,
    int histBlocks, int fuseBlocks,
    const int* __restrict__ ei, int E, int* __restrict__ bucketTot, int nbuck) {
  int b = blockIdx.x;
  int t = threadIdx.x;
  if (b < histBlocks) {
    __shared__ int h[512];
    h[t] = 0; h[t + 256] = 0;
    __syncthreads();
    int e0 = b * 4096;
#pragma unroll 4
    for (int i = 0; i < 16; ++i) {
      int e = e0 + t + i * 256;
      if (e < E) atomicAdd(&h[ei[E + e] >> 8], 1);
    }
    __syncthreads();
    if (t < nbuck && h[t]) atomicAdd(bucketTot + t, h[t]);
    if (t + 256 < nbuck && h[t + 256]) atomicAdd(bucketTot + t + 256, h[t + 256]);
    return;
  }
  b -= histBlocks;
  if (b < fuseBlocks) {
    mfma_gemm_body<true, false, false, 24, 8>(Wlin, 768, blin, nullptr, W1, 768,
                                              nullptr, WfuseB, 301, b * 4 + (t >> 6));
    return;
  }
  b -= fuseBlocks;
  if (b < 24) { pack_w_body<false>(W1, 768, 24, packW1, b * 256 + t); return; }
  b -= 24;
  pack_w_body<true>(W2, 64, 2, packW2, b * 256 + t);
}

// k_scanB: block 0 = exclusive scan of bucketTot -> bucketBase/bucketRun;
//          blocks 1..5 = pack WfuseB (rows 0..299) -> bf16 fragments.
__global__ __launch_bounds__(512) void k_scanB(
    const int* __restrict__ bucketTot, int nbuck,
    int* __restrict__ bucketBase, int* __restrict__ bucketRun,
    const float* __restrict__ WfuseB, unsigned short* __restrict__ packWf) {
  int t = threadIdx.x;
  if (blockIdx.x > 0) {
    pack_w_body<false>(WfuseB, 300, 10, packWf, ((int)blockIdx.x - 1) * 512 + t);
    return;
  }
  __shared__ int s[512];
  int v = (t < nbuck) ? bucketTot[t] : 0;
  s[t] = v; __syncthreads();
  for (int off = 1; off < 512; off <<= 1) {
    int x = (t >= off) ? s[t - off] : 0;
    __syncthreads();
    s[t] += x;
    __syncthreads();
  }
  if (t < nbuck) {
    int ex = s[t] - v;
    bucketBase[t] = ex;
    bucketRun[t] = ex;
  }
  if (t == nbuck - 1) bucketBase[nbuck] = s[t];   // = E
}

// k_sd: [scatBlocks) scatter edges into bucket-grouped ebuf (LDS ranks, one
// run-reservation atomic per non-empty (block,bucket)); rest: doc GEMM.
__global__ __launch_bounds__(256) void k_sd(
    const int* __restrict__ ei, const float* __restrict__ ew, int E,
    int scatBlocks, int* __restrict__ bucketRun, int2* __restrict__ ebuf,
    const float* __restrict__ doc, const unsigned short* __restrict__ packW1,
    unsigned short* __restrict__ xw1, int ND) {
  int b = blockIdx.x;
  int t = threadIdx.x;
  if (b >= scatBlocks) {
    mfma_gemm_body<false, true, true, 24, 8>(doc, 768, nullptr, packW1, nullptr, 768,
                                             nullptr, xw1, ND, (b - scatBlocks) * 4 + (t >> 6));
    return;
  }
  __shared__ int h[512];
  __shared__ int base[512];
  __shared__ int cur[512];
  h[t] = 0; h[t + 256] = 0;
  __syncthreads();
  int e0 = b * 4096;
#pragma unroll 4
  for (int i = 0; i < 16; ++i) {
    int e = e0 + t + i * 256;
    if (e < E) atomicAdd(&h[ei[E + e] >> 8], 1);
  }
  __syncthreads();
#pragma unroll
  for (int k = t; k < 512; k += 256) {
    if (h[k]) base[k] = atomicAdd(bucketRun + k, h[k]);
    cur[k] = 0;
  }
  __syncthreads();
#pragma unroll 4
  for (int i = 0; i < 16; ++i) {
    int e = e0 + t + i * 256;
    if (e < E) {
      int d = ei[E + e];
      int bk = d >> 8;
      int r = base[bk] + atomicAdd(&cur[bk], 1);
      ebuf[r] = make_int2(ei[e] | ((d & 255) << 17), __float_as_int(ew[e]));
    }
  }
}

// k_bw: [nbuck) per-bucket CSR build (LDS cnt/wdeg/scan -> contiguous
// entries slice + offs + dis); rest: word GEMM.
__global__ __launch_bounds__(256) void k_bw(
    const int2* __restrict__ ebuf, const int* __restrict__ bucketBase,
    int nbuck, int N, int* __restrict__ offs, float* __restrict__ dis,
    int2* __restrict__ entries,
    const float* __restrict__ wordf, const unsigned short* __restrict__ packWf,
    const float* __restrict__ bfuse, unsigned short* __restrict__ xw1word, int NW) {
  int b = blockIdx.x;
  int t = threadIdx.x;
  if (b >= nbuck) {
    mfma_gemm_body<false, true, true, 10, 5>(wordf, 300, nullptr, packWf, nullptr, 300,
                                             bfuse, xw1word, NW, (b - nbuck) * 4 + (t >> 6));
    return;
  }
  __shared__ int scnt[256];
  __shared__ float swd[256];
  __shared__ int sscan[256];
  __shared__ int scur[256];
  int node0 = b << 8;
  int nn = min(256, N - node0);
  int estart = bucketBase[b], eend = bucketBase[b + 1];
  scnt[t] = (t < nn) ? 1 : 0;          // self loop
  swd[t] = (t < nn) ? 1.f : 0.f;       // self weight
  __syncthreads();
  for (int p = estart + t; p < eend; p += 256) {
    int2 e = ebuf[p];
    int low = (e.x >> 17) & 255;
    atomicAdd(&scnt[low], 1);
    atomicAdd(&swd[low], __int_as_float(e.y));
  }
  __syncthreads();
  int v = scnt[t];
  sscan[t] = v; __syncthreads();
  for (int off = 1; off < 256; off <<= 1) {
    int x = (t >= off) ? sscan[t - off] : 0;
    __syncthreads();
    sscan[t] += x;
    __syncthreads();
  }
  int excl = sscan[t] - v;
  int entriesBase = estart + node0;    // edges-before + selfs-before
  if (t < nn) {
    offs[node0 + t] = entriesBase + excl;
    dis[node0 + t] = rsqrtf(fmaxf(swd[t], 1e-12f));
    entries[entriesBase + excl] = make_int2(node0 + t, __float_as_int(1.0f));
  }
  scur[t] = excl + 1;
  if (t == 0 && b == nbuck - 1) offs[N] = entriesBase + (eend - estart) + nn;
  __syncthreads();
  for (int p = estart + t; p < eend; p += 256) {
    int2 e = ebuf[p];
    int low = (e.x >> 17) & 255;
    int r = atomicAdd(&scur[low], 1);
    entries[entriesBase + r] = make_int2(e.x & 0x1FFFF, e.y);
  }
}

// half-wave gather-accumulate: 32 lanes, each lane covers 2 cols (ushort2).
// entries hold RAW w -> multiply dis[src] per entry (broadcast, L2-hot).
__device__ __forceinline__ void row_gather2(const unsigned short* __restrict__ xin,
                                            const int2* __restrict__ entries,
                                            const float* __restrict__ dis,
                                            int p, int pe, int l32,
                                            float& ra0, float& ra1) {
  float a0 = 0.f, a1 = 0.f;
  for (; p + 8 <= pe; p += 8) {
    int2 e[8];
#pragma unroll
    for (int j = 0; j < 8; ++j) e[j] = entries[p + j];
    unsigned x[8];
    float ds[8];
#pragma unroll
    for (int j = 0; j < 8; ++j) {
      x[j] = *(const unsigned*)(xin + ((size_t)e[j].x << 6) + (l32 << 1));
      ds[j] = dis[e[j].x];
    }
#pragma unroll
    for (int j = 0; j < 8; ++j) {
      float w = __int_as_float(e[j].y) * ds[j];
      a0 = fmaf(bf2f((unsigned short)(x[j] & 0xffffu)), w, a0);
      a1 = fmaf(bf2f((unsigned short)(x[j] >> 16)), w, a1);
    }
  }
  if (p + 4 <= pe) {
    int2 e[4];
#pragma unroll
    for (int j = 0; j < 4; ++j) e[j] = entries[p + j];
    unsigned x[4];
    float ds[4];
#pragma unroll
    for (int j = 0; j < 4; ++j) {
      x[j] = *(const unsigned*)(xin + ((size_t)e[j].x << 6) + (l32 << 1));
      ds[j] = dis[e[j].x];
    }
#pragma unroll
    for (int j = 0; j < 4; ++j) {
      float w = __int_as_float(e[j].y) * ds[j];
      a0 = fmaf(bf2f((unsigned short)(x[j] & 0xffffu)), w, a0);
      a1 = fmaf(bf2f((unsigned short)(x[j] >> 16)), w, a1);
    }
    p += 4;
  }
  for (; p < pe; ++p) {
    int2 e = entries[p];
    unsigned x = *(const unsigned*)(xin + ((size_t)e.x << 6) + (l32 << 1));
    float w = __int_as_float(e.y) * dis[e.x];
    a0 = fmaf(bf2f((unsigned short)(x & 0xffffu)), w, a0);
    a1 = fmaf(bf2f((unsigned short)(x >> 16)), w, a1);
  }
  ra0 = a0; ra1 = a1;
}

// layer-1 aggregation: half-wave per node, ushort2 out (permuted pos layout)
__global__ void k_agg(const unsigned short* __restrict__ xin, const int2* __restrict__ entries,
                      const int* __restrict__ offs, const float* __restrict__ dis,
                      const float* __restrict__ bias, unsigned short* __restrict__ xout, int N) {
  const int tid = threadIdx.x;
  const int l32 = tid & 31;
  int i = blockIdx.x * 8 + (tid >> 5);
  if (i >= N) return;
  float a0, a1;
  row_gather2(xin, entries, dis, offs[i], offs[i + 1], l32, a0, a1);
  float d = dis[i];
  a0 = fmaxf(fmaf(a0, d, bias[permcol(2 * l32)]), 0.f);
  a1 = fmaxf(fmaf(a1, d, bias[permcol(2 * l32 + 1)]), 0.f);
  ushort2 pk;
  pk.x = f2bf(a0);
  pk.y = f2bf(a1);
  *(ushort2*)(xout + ((size_t)i << 6) + (l32 << 1)) = pk;
}

// masked layer-2 aggregation: half-wave per masked node, fp32 out + y[mask]
__global__ void k_agg2m(const unsigned short* __restrict__ xin, const int2* __restrict__ entries,
                        const int* __restrict__ offs, const float* __restrict__ dis,
                        const int* __restrict__ mask, const int* __restrict__ y,
                        float* __restrict__ tout, float* __restrict__ outY, int M) {
  const int tid = threadIdx.x;
  const int l32 = tid & 31;
  int o = blockIdx.x * 8 + (tid >> 5);
  if (o >= M) return;
  int i = mask[o];
  float a0, a1;
  row_gather2(xin, entries, dis, offs[i], offs[i + 1], l32, a0, a1);
  float d = dis[i];
  float2 pk;
  pk.x = a0 * d;
  pk.y = a1 * d;
  *(float2*)(tout + ((size_t)o << 6) + (l32 << 1)) = pk;
  if (l32 == 0) outY[o] = (float)y[i];
}

// final projection [M,64]@[64,64]+b2 via MFMA (permuted-k packed W2), fp32 out
__global__ __launch_bounds__(256) void k_mfma_final(
    const float* __restrict__ X, const unsigned short* __restrict__ packW2,
    const float* __restrict__ b2, float* __restrict__ out, int M) {
  mfma_gemm_body<false, true, false, 2, 2>(X, 64, nullptr, packW2, nullptr, 64,
                                           b2, out, M, blockIdx.x * 4 + (threadIdx.x >> 6));
}

extern "C" void kernel_launch(void* const* d_in, const int* in_sizes, int n_in,
                              void* d_out, int out_size, void* d_ws, size_t ws_size,
                              hipStream_t stream) {
  const float* doc   = (const float*)d_in[0];
  const float* wordf = (const float*)d_in[1];
  const float* ew    = (const float*)d_in[2];
  const float* Wlin  = (const float*)d_in[3];
  const float* blin  = (const float*)d_in[4];
  const float* W1    = (const float*)d_in[5];
  const float* b1    = (const float*)d_in[6];
  const float* W2    = (const float*)d_in[7];
  const float* b2    = (const float*)d_in[8];
  const int*   ei    = (const int*)d_in[9];
  const int*   mask  = (const int*)d_in[10];
  const int*   y     = (const int*)d_in[11];

  const int E  = in_sizes[2];
  const int M  = in_sizes[10];
  const int ND = in_sizes[0] / 768;
  const int NW = in_sizes[1] / 300;
  const int N  = ND + NW;
  const int NE = N + E;
  const int nbuck = (N + 255) >> 8;          // <= 512 (N <= 131072)

  // workspace carve (aligned 256B)
  char* p = (char*)d_ws;
  auto carve = [&](size_t bytes) -> void* {
    void* q = (void*)p;
    p += (bytes + 255) & ~(size_t)255;
    return q;
  };
  float*          WfuseB = (float*)carve(301 * 64 * 4);
  unsigned short* packW1 = (unsigned short*)carve((size_t)4 * 24 * 64 * 8 * 2);
  unsigned short* packW2 = (unsigned short*)carve((size_t)4 * 2 * 64 * 8 * 2);
  unsigned short* packWf = (unsigned short*)carve((size_t)4 * 10 * 64 * 8 * 2);
  float* dis       = (float*)carve((size_t)N * 4);
  int*   offs      = (int*)carve(((size_t)N + 1) * 4);
  int*   bucketTot = (int*)carve((size_t)(nbuck + 2) * 4);
  int*   bucketBase= (int*)carve((size_t)(nbuck + 2) * 4);
  int*   bucketRun = (int*)carve((size_t)(nbuck + 2) * 4);
  int2*  ebuf      = (int2*)carve((size_t)E * 8);
  int2*  entries   = (int2*)carve((size_t)NE * 8);
  unsigned short* xw1 = (unsigned short*)carve((size_t)N * 64 * 2);  // bf16, permuted
  unsigned short* h1  = (unsigned short*)carve((size_t)N * 64 * 2);  // bf16, permuted
  float* tmask = (float*)carve((size_t)M * 64 * 4);                  // fp32, permuted

  hipMemsetAsync(bucketTot, 0, (size_t)nbuck * 4, stream);

  // k_pre: bucket hist || fuse MFMA || pack W1 || pack W2
  const int fuseBlocks = (301 + 63) / 64;    // 16 rows/wave
  const int histBlocks = (E + 4095) / 4096;
  k_pre<<<histBlocks + fuseBlocks + 24 + 2, 256, 0, stream>>>(
      Wlin, blin, W1, WfuseB, packW1, W2, packW2,
      histBlocks, fuseBlocks, ei, E, bucketTot, nbuck);

  // bucket scan || packWf  (block 0 scan; blocks 1..5 pack 2560 threads)
  k_scanB<<<6, 512, 0, stream>>>(bucketTot, nbuck, bucketBase, bucketRun,
                                 WfuseB, packWf);

  // scatter || doc GEMM
  const int docBlocks  = (ND + 63) / 64;
  k_sd<<<histBlocks + docBlocks, 256, 0, stream>>>(
      ei, ew, E, histBlocks, bucketRun, ebuf,
      doc, packW1, xw1, ND);

  // per-bucket CSR build || word GEMM
  const int wordBlocks = (NW + 63) / 64;     // 5000 waves (~20/CU)
  k_bw<<<nbuck + wordBlocks, 256, 0, stream>>>(
      ebuf, bucketBase, nbuck, N, offs, dis, entries,
      wordf, packWf, WfuseB + (size_t)300 * 64, xw1 + (size_t)ND * 64, NW);

  // layer-1 aggregation (+b1 via pi, relu) -> bf16 h1 (permuted)
  k_agg<<<(N + 7) / 8, 256, 0, stream>>>(xw1, entries, offs, dis, b1, h1, N);

  // layer-2: masked aggregation over h1, then project [M,64]@[64,64]+b2
  float* out0 = (float*)d_out;
  float* outY = out0 + (size_t)M * 64;
  k_agg2m<<<(M + 7) / 8, 256, 0, stream>>>(h1, entries, offs, dis, mask, y, tmask, outY, M);
  k_mfma_final<<<(M + 63) / 64, 256, 0, stream>>>(tmask, packW2, b2, out0, M);
}

// Round 7
// 327.714 us; speedup vs baseline: 1.3213x; 1.0338x over previous
//
#include <hip/hip_runtime.h>

// ---------------------------------------------------------------------------
// TextGCN (2-layer GCN, eval mode) on MI355X.
// Fusions:
//   * xw1_word = word @ (W_lin@W1) + (b_lin@W1)  (never materialize [N,768] x)
//   * layer 2: agg(h1@W2)[mask] == agg(h1)[mask] @ W2
// CSR BUILD = 2-LEVEL BUCKET SORT (no scattered-megaop atomics):
//   r3 measured: scattered 4-8B atomics/writes cost 32B HBM sectors at
//   ~550 GB/s. LDS bucket histograms (dst>>8), dense run writes to ebuf,
//   per-bucket contiguous CSR build. Entries hold RAW w; agg multiplies
//   dis[src] (L2-hot) and dis[dst] at the end.
// GEMM MLP (r5/r6): grid-occupancy fix (16 rows/wave) + CHUNK-deep A-load
//   hoist (issue all CHUNK k0 A-loads back-to-back, then convert+MFMA).
//   r6 measured: CHUNK hoist + PACKED=false strided B = pathological
//   (a[8][8] pins 64 VGPRs -> compiler serializes 768 strided B loads at
//   L2 latency -> 80us fuse tail at 1.5% occupancy). Fix: k_pack packs
//   W1/W2 FIRST (tiny), fuse consumes packW1 (PACKED=true). No strided-B
//   GEMM path remains anywhere.
// PIPELINE:
//   memset(1.6KB) -> k_pack(packW1||packW2, 26 blks) ->
//   k_pre(bucketHist || fuseGEMM-packed) -> k_scanB(bucket scan || packWf)
//   -> k_sd(scatter || docGEMM) -> k_bw(bucketBuild || wordGEMM) ->
//   k_agg -> k_agg2m -> k_mfma_final
// xw1/h1 bf16 in PERMUTED column order pi(pos)=(pos&3)*16+(pos>>2) (coalesced
// 8B MFMA epilogue stores). b1 indexed via pi; packW2 k-rows permuted via pi.
// ebuf record: {src | (dst&255)<<17, w}  (src < 2^17 since N <= 131072).
// ---------------------------------------------------------------------------

typedef __attribute__((ext_vector_type(8))) short short8;   // 8 bf16 = 4 VGPR
typedef __attribute__((ext_vector_type(4))) float float4v;  // MFMA C/D frag

__device__ __forceinline__ unsigned short f2bf(float f) {   // RNE f32->bf16
  unsigned u = __float_as_uint(f);
  return (unsigned short)((u + 0x7FFFu + ((u >> 16) & 1u)) >> 16);
}
__device__ __forceinline__ float bf2f(unsigned short u) {
  return __uint_as_float((unsigned)u << 16);
}
__device__ __forceinline__ int permcol(int p) {   // pi: pos -> true col
  return ((p & 3) << 4) | (p >> 2);
}

// pack W[K,64] fp32 -> bf16 fragment order: pack[((g*nk0+k0)*64+lane)*8+j]
// holds W[ksrc][(lane&15)+16g], ksrc = PERM ? pi(k) : k; zero past K.
template <bool PERM>
__device__ __forceinline__ void pack_w_body(const float* __restrict__ W, int K,
                                            int nk0, unsigned short* __restrict__ pack,
                                            int tid) {
  int lane = tid & 63;
  int rest = tid >> 6;
  int k0 = rest % nk0;
  int g = rest / nk0;
  int quad = lane >> 4;
  int n = (lane & 15) + g * 16;
  short8 v;
#pragma unroll
  for (int j = 0; j < 8; ++j) {
    int k = k0 * 32 + quad * 8 + j;
    int ks = PERM ? permcol(k) : k;
    float w = (k < K) ? W[(size_t)ks * 64 + n] : 0.f;
    v[j] = (short)f2bf(w);
  }
  *(short8*)(pack + (((size_t)(g * nk0 + k0) * 64 + lane) << 3)) = v;
}

// MFMA GEMM: out[R,64] = X[R,K(ldx)] @ W[K,64] (+bias). One wave = 16 rows.
// NK0/CHUNK compile-time: A-loads for CHUNK k0s issued back-to-back (deep
// MLP, few stalls/wave), then the chunk's convert+MFMA. B always from packed
// bf16 fragments (L2-hot).
template <bool LAST, bool BF16PERM, int NK0, int CHUNK>
__device__ __forceinline__ void mfma_gemm_body(
    const float* __restrict__ X, int ldx, const float* __restrict__ lastRow,
    const unsigned short* __restrict__ Wpack,
    int K, const float* __restrict__ bias,
    void* __restrict__ outv, int R, int waveIdx) {
  int r0 = waveIdx * 16;
  if (r0 >= R) return;
  const int lane = threadIdx.x & 63;
  const int quad = lane >> 4;
  const int m = lane & 15;
  const float* xrow = nullptr;
  {
    int row = r0 + m;
    if (row < R) xrow = (LAST && row == R - 1) ? lastRow : X + (size_t)row * ldx;
  }

  float4v acc[4];
#pragma unroll
  for (int g = 0; g < 4; ++g) acc[g] = (float4v){0.f, 0.f, 0.f, 0.f};

#pragma unroll
  for (int c0 = 0; c0 < NK0; c0 += CHUNK) {
    // ---- A-hoist: all CHUNK k0 loads, no dependent compute between ----
    float a[CHUNK][8];
#pragma unroll
    for (int cc = 0; cc < CHUNK; ++cc) {
      int kb = (c0 + cc) * 32 + quad * 8;
      if (xrow && kb + 8 <= K) {
        float4 v0 = *(const float4*)(xrow + kb);
        float4 v1 = *(const float4*)(xrow + kb + 4);
        a[cc][0] = v0.x; a[cc][1] = v0.y; a[cc][2] = v0.z; a[cc][3] = v0.w;
        a[cc][4] = v1.x; a[cc][5] = v1.y; a[cc][6] = v1.z; a[cc][7] = v1.w;
      } else {
#pragma unroll
        for (int j = 0; j < 8; ++j) {
          int k = kb + j;
          a[cc][j] = (xrow && k < K) ? xrow[k] : 0.f;
        }
      }
    }
    // ---- compute the chunk (packed bf16 B fragments) ----
#pragma unroll
    for (int cc = 0; cc < CHUNK; ++cc) {
      int k0 = c0 + cc;
      short8 bf[4];
#pragma unroll
      for (int g = 0; g < 4; ++g)
        bf[g] = *(const short8*)(Wpack + (((size_t)(g * NK0 + k0) * 64 + lane) << 3));
      short8 af;
#pragma unroll
      for (int j = 0; j < 8; ++j) af[j] = (short)f2bf(a[cc][j]);
#pragma unroll
      for (int g = 0; g < 4; ++g)
        acc[g] = __builtin_amdgcn_mfma_f32_16x16x32_bf16(af, bf[g], acc[g], 0, 0, 0);
    }
  }

  // ---- epilogue ----
  if (BF16PERM) {
    // lane m packs cols {m,16+m,32+m,48+m} of row r0+quad*4+j as 4 bf16 (8B)
    float b0 = bias ? bias[m] : 0.f;
    float b1 = bias ? bias[16 + m] : 0.f;
    float b2 = bias ? bias[32 + m] : 0.f;
    float b3 = bias ? bias[48 + m] : 0.f;
#pragma unroll
    for (int j = 0; j < 4; ++j) {
      int r = r0 + quad * 4 + j;
      if (r < R) {
        ushort4 pk;
        pk.x = f2bf(acc[0][j] + b0);
        pk.y = f2bf(acc[1][j] + b1);
        pk.z = f2bf(acc[2][j] + b2);
        pk.w = f2bf(acc[3][j] + b3);
        *(ushort4*)((unsigned short*)outv + ((size_t)r * 64 + m * 4)) = pk;
      }
    }
  } else {
#pragma unroll
    for (int g = 0; g < 4; ++g) {
      float b = bias ? bias[g * 16 + m] : 0.f;
#pragma unroll
      for (int reg = 0; reg < 4; ++reg) {
        int r = r0 + quad * 4 + reg;   // C/D: col=lane&15, row=quad*4+reg
        if (r < R) ((float*)outv)[(size_t)r * 64 + g * 16 + m] = acc[g][reg] + b;
      }
    }
  }
}

// k_pack: [24) pack W1; [+2) pack W2 (permuted k). Tiny (212KB read).
__global__ __launch_bounds__(256) void k_pack(
    const float* __restrict__ W1, unsigned short* __restrict__ packW1,
    const float* __restrict__ W2, unsigned short* __restrict__ packW2) {
  int b = blockIdx.x;
  int t = threadIdx.x;
  if (b < 24) { pack_w_body<false>(W1, 768, 24, packW1, b * 256 + t); return; }
  b -= 24;
  pack_w_body<true>(W2, 64, 2, packW2, b * 256 + t);
}

// k_pre: [histBlocks) bucket histogram (LDS, flush <=nbuck atomics/block);
//        rest: fuse GEMM [Wlin;blin]@W1 -> WfuseB via PACKED packW1.
__global__ __launch_bounds__(256) void k_pre(
    const float* __restrict__ Wlin, const float* __restrict__ blin,
    const unsigned short* __restrict__ packW1, float* __restrict__ WfuseB,
    int histBlocks,
    const int* __restrict__ ei, int E, int* __restrict__ bucketTot, int nbuck) {
  int b = blockIdx.x;
  int t = threadIdx.x;
  if (b < histBlocks) {
    __shared__ int h[512];
    h[t] = 0; h[t + 256] = 0;
    __syncthreads();
    int e0 = b * 4096;
#pragma unroll 4
    for (int i = 0; i < 16; ++i) {
      int e = e0 + t + i * 256;
      if (e < E) atomicAdd(&h[ei[E + e] >> 8], 1);
    }
    __syncthreads();
    if (t < nbuck && h[t]) atomicAdd(bucketTot + t, h[t]);
    if (t + 256 < nbuck && h[t + 256]) atomicAdd(bucketTot + t + 256, h[t + 256]);
    return;
  }
  b -= histBlocks;
  mfma_gemm_body<true, false, 24, 8>(Wlin, 768, blin, packW1, 768,
                                     nullptr, WfuseB, 301, b * 4 + (t >> 6));
}

// k_scanB: block 0 = exclusive scan of bucketTot -> bucketBase/bucketRun;
//          blocks 1..5 = pack WfuseB (rows 0..299) -> bf16 fragments.
__global__ __launch_bounds__(512) void k_scanB(
    const int* __restrict__ bucketTot, int nbuck,
    int* __restrict__ bucketBase, int* __restrict__ bucketRun,
    const float* __restrict__ WfuseB, unsigned short* __restrict__ packWf) {
  int t = threadIdx.x;
  if (blockIdx.x > 0) {
    pack_w_body<false>(WfuseB, 300, 10, packWf, ((int)blockIdx.x - 1) * 512 + t);
    return;
  }
  __shared__ int s[512];
  int v = (t < nbuck) ? bucketTot[t] : 0;
  s[t] = v; __syncthreads();
  for (int off = 1; off < 512; off <<= 1) {
    int x = (t >= off) ? s[t - off] : 0;
    __syncthreads();
    s[t] += x;
    __syncthreads();
  }
  if (t < nbuck) {
    int ex = s[t] - v;
    bucketBase[t] = ex;
    bucketRun[t] = ex;
  }
  if (t == nbuck - 1) bucketBase[nbuck] = s[t];   // = E
}

// k_sd: [scatBlocks) scatter edges into bucket-grouped ebuf (LDS ranks, one
// run-reservation atomic per non-empty (block,bucket)); rest: doc GEMM.
__global__ __launch_bounds__(256) void k_sd(
    const int* __restrict__ ei, const float* __restrict__ ew, int E,
    int scatBlocks, int* __restrict__ bucketRun, int2* __restrict__ ebuf,
    const float* __restrict__ doc, const unsigned short* __restrict__ packW1,
    unsigned short* __restrict__ xw1, int ND) {
  int b = blockIdx.x;
  int t = threadIdx.x;
  if (b >= scatBlocks) {
    mfma_gemm_body<false, true, 24, 8>(doc, 768, nullptr, packW1, 768,
                                       nullptr, xw1, ND, (b - scatBlocks) * 4 + (t >> 6));
    return;
  }
  __shared__ int h[512];
  __shared__ int base[512];
  __shared__ int cur[512];
  h[t] = 0; h[t + 256] = 0;
  __syncthreads();
  int e0 = b * 4096;
#pragma unroll 4
  for (int i = 0; i < 16; ++i) {
    int e = e0 + t + i * 256;
    if (e < E) atomicAdd(&h[ei[E + e] >> 8], 1);
  }
  __syncthreads();
#pragma unroll
  for (int k = t; k < 512; k += 256) {
    if (h[k]) base[k] = atomicAdd(bucketRun + k, h[k]);
    cur[k] = 0;
  }
  __syncthreads();
#pragma unroll 4
  for (int i = 0; i < 16; ++i) {
    int e = e0 + t + i * 256;
    if (e < E) {
      int d = ei[E + e];
      int bk = d >> 8;
      int r = base[bk] + atomicAdd(&cur[bk], 1);
      ebuf[r] = make_int2(ei[e] | ((d & 255) << 17), __float_as_int(ew[e]));
    }
  }
}

// k_bw: [nbuck) per-bucket CSR build (LDS cnt/wdeg/scan -> contiguous
// entries slice + offs + dis); rest: word GEMM.
__global__ __launch_bounds__(256) void k_bw(
    const int2* __restrict__ ebuf, const int* __restrict__ bucketBase,
    int nbuck, int N, int* __restrict__ offs, float* __restrict__ dis,
    int2* __restrict__ entries,
    const float* __restrict__ wordf, const unsigned short* __restrict__ packWf,
    const float* __restrict__ bfuse, unsigned short* __restrict__ xw1word, int NW) {
  int b = blockIdx.x;
  int t = threadIdx.x;
  if (b >= nbuck) {
    mfma_gemm_body<false, true, 10, 5>(wordf, 300, nullptr, packWf, 300,
                                       bfuse, xw1word, NW, (b - nbuck) * 4 + (t >> 6));
    return;
  }
  __shared__ int scnt[256];
  __shared__ float swd[256];
  __shared__ int sscan[256];
  __shared__ int scur[256];
  int node0 = b << 8;
  int nn = min(256, N - node0);
  int estart = bucketBase[b], eend = bucketBase[b + 1];
  scnt[t] = (t < nn) ? 1 : 0;          // self loop
  swd[t] = (t < nn) ? 1.f : 0.f;       // self weight
  __syncthreads();
  for (int p = estart + t; p < eend; p += 256) {
    int2 e = ebuf[p];
    int low = (e.x >> 17) & 255;
    atomicAdd(&scnt[low], 1);
    atomicAdd(&swd[low], __int_as_float(e.y));
  }
  __syncthreads();
  int v = scnt[t];
  sscan[t] = v; __syncthreads();
  for (int off = 1; off < 256; off <<= 1) {
    int x = (t >= off) ? sscan[t - off] : 0;
    __syncthreads();
    sscan[t] += x;
    __syncthreads();
  }
  int excl = sscan[t] - v;
  int entriesBase = estart + node0;    // edges-before + selfs-before
  if (t < nn) {
    offs[node0 + t] = entriesBase + excl;
    dis[node0 + t] = rsqrtf(fmaxf(swd[t], 1e-12f));
    entries[entriesBase + excl] = make_int2(node0 + t, __float_as_int(1.0f));
  }
  scur[t] = excl + 1;
  if (t == 0 && b == nbuck - 1) offs[N] = entriesBase + (eend - estart) + nn;
  __syncthreads();
  for (int p = estart + t; p < eend; p += 256) {
    int2 e = ebuf[p];
    int low = (e.x >> 17) & 255;
    int r = atomicAdd(&scur[low], 1);
    entries[entriesBase + r] = make_int2(e.x & 0x1FFFF, e.y);
  }
}

// half-wave gather-accumulate: 32 lanes, each lane covers 2 cols (ushort2).
// entries hold RAW w -> multiply dis[src] per entry (broadcast, L2-hot).
__device__ __forceinline__ void row_gather2(const unsigned short* __restrict__ xin,
                                            const int2* __restrict__ entries,
                                            const float* __restrict__ dis,
                                            int p, int pe, int l32,
                                            float& ra0, float& ra1) {
  float a0 = 0.f, a1 = 0.f;
  for (; p + 8 <= pe; p += 8) {
    int2 e[8];
#pragma unroll
    for (int j = 0; j < 8; ++j) e[j] = entries[p + j];
    unsigned x[8];
    float ds[8];
#pragma unroll
    for (int j = 0; j < 8; ++j) {
      x[j] = *(const unsigned*)(xin + ((size_t)e[j].x << 6) + (l32 << 1));
      ds[j] = dis[e[j].x];
    }
#pragma unroll
    for (int j = 0; j < 8; ++j) {
      float w = __int_as_float(e[j].y) * ds[j];
      a0 = fmaf(bf2f((unsigned short)(x[j] & 0xffffu)), w, a0);
      a1 = fmaf(bf2f((unsigned short)(x[j] >> 16)), w, a1);
    }
  }
  if (p + 4 <= pe) {
    int2 e[4];
#pragma unroll
    for (int j = 0; j < 4; ++j) e[j] = entries[p + j];
    unsigned x[4];
    float ds[4];
#pragma unroll
    for (int j = 0; j < 4; ++j) {
      x[j] = *(const unsigned*)(xin + ((size_t)e[j].x << 6) + (l32 << 1));
      ds[j] = dis[e[j].x];
    }
#pragma unroll
    for (int j = 0; j < 4; ++j) {
      float w = __int_as_float(e[j].y) * ds[j];
      a0 = fmaf(bf2f((unsigned short)(x[j] & 0xffffu)), w, a0);
      a1 = fmaf(bf2f((unsigned short)(x[j] >> 16)), w, a1);
    }
    p += 4;
  }
  for (; p < pe; ++p) {
    int2 e = entries[p];
    unsigned x = *(const unsigned*)(xin + ((size_t)e.x << 6) + (l32 << 1));
    float w = __int_as_float(e.y) * dis[e.x];
    a0 = fmaf(bf2f((unsigned short)(x & 0xffffu)), w, a0);
    a1 = fmaf(bf2f((unsigned short)(x >> 16)), w, a1);
  }
  ra0 = a0; ra1 = a1;
}

// layer-1 aggregation: half-wave per node, ushort2 out (permuted pos layout)
__global__ void k_agg(const unsigned short* __restrict__ xin, const int2* __restrict__ entries,
                      const int* __restrict__ offs, const float* __restrict__ dis,
                      const float* __restrict__ bias, unsigned short* __restrict__ xout, int N) {
  const int tid = threadIdx.x;
  const int l32 = tid & 31;
  int i = blockIdx.x * 8 + (tid >> 5);
  if (i >= N) return;
  float a0, a1;
  row_gather2(xin, entries, dis, offs[i], offs[i + 1], l32, a0, a1);
  float d = dis[i];
  a0 = fmaxf(fmaf(a0, d, bias[permcol(2 * l32)]), 0.f);
  a1 = fmaxf(fmaf(a1, d, bias[permcol(2 * l32 + 1)]), 0.f);
  ushort2 pk;
  pk.x = f2bf(a0);
  pk.y = f2bf(a1);
  *(ushort2*)(xout + ((size_t)i << 6) + (l32 << 1)) = pk;
}

// masked layer-2 aggregation: half-wave per masked node, fp32 out + y[mask]
__global__ void k_agg2m(const unsigned short* __restrict__ xin, const int2* __restrict__ entries,
                        const int* __restrict__ offs, const float* __restrict__ dis,
                        const int* __restrict__ mask, const int* __restrict__ y,
                        float* __restrict__ tout, float* __restrict__ outY, int M) {
  const int tid = threadIdx.x;
  const int l32 = tid & 31;
  int o = blockIdx.x * 8 + (tid >> 5);
  if (o >= M) return;
  int i = mask[o];
  float a0, a1;
  row_gather2(xin, entries, dis, offs[i], offs[i + 1], l32, a0, a1);
  float d = dis[i];
  float2 pk;
  pk.x = a0 * d;
  pk.y = a1 * d;
  *(float2*)(tout + ((size_t)o << 6) + (l32 << 1)) = pk;
  if (l32 == 0) outY[o] = (float)y[i];
}

// final projection [M,64]@[64,64]+b2 via MFMA (permuted-k packed W2), fp32 out
__global__ __launch_bounds__(256) void k_mfma_final(
    const float* __restrict__ X, const unsigned short* __restrict__ packW2,
    const float* __restrict__ b2, float* __restrict__ out, int M) {
  mfma_gemm_body<false, false, 2, 2>(X, 64, nullptr, packW2, 64,
                                     b2, out, M, blockIdx.x * 4 + (threadIdx.x >> 6));
}

extern "C" void kernel_launch(void* const* d_in, const int* in_sizes, int n_in,
                              void* d_out, int out_size, void* d_ws, size_t ws_size,
                              hipStream_t stream) {
  const float* doc   = (const float*)d_in[0];
  const float* wordf = (const float*)d_in[1];
  const float* ew    = (const float*)d_in[2];
  const float* Wlin  = (const float*)d_in[3];
  const float* blin  = (const float*)d_in[4];
  const float* W1    = (const float*)d_in[5];
  const float* b1    = (const float*)d_in[6];
  const float* W2    = (const float*)d_in[7];
  const float* b2    = (const float*)d_in[8];
  const int*   ei    = (const int*)d_in[9];
  const int*   mask  = (const int*)d_in[10];
  const int*   y     = (const int*)d_in[11];

  const int E  = in_sizes[2];
  const int M  = in_sizes[10];
  const int ND = in_sizes[0] / 768;
  const int NW = in_sizes[1] / 300;
  const int N  = ND + NW;
  const int NE = N + E;
  const int nbuck = (N + 255) >> 8;          // <= 512 (N <= 131072)

  // workspace carve (aligned 256B)
  char* p = (char*)d_ws;
  auto carve = [&](size_t bytes) -> void* {
    void* q = (void*)p;
    p += (bytes + 255) & ~(size_t)255;
    return q;
  };
  float*          WfuseB = (float*)carve(301 * 64 * 4);
  unsigned short* packW1 = (unsigned short*)carve((size_t)4 * 24 * 64 * 8 * 2);
  unsigned short* packW2 = (unsigned short*)carve((size_t)4 * 2 * 64 * 8 * 2);
  unsigned short* packWf = (unsigned short*)carve((size_t)4 * 10 * 64 * 8 * 2);
  float* dis       = (float*)carve((size_t)N * 4);
  int*   offs      = (int*)carve(((size_t)N + 1) * 4);
  int*   bucketTot = (int*)carve((size_t)(nbuck + 2) * 4);
  int*   bucketBase= (int*)carve((size_t)(nbuck + 2) * 4);
  int*   bucketRun = (int*)carve((size_t)(nbuck + 2) * 4);
  int2*  ebuf      = (int2*)carve((size_t)E * 8);
  int2*  entries   = (int2*)carve((size_t)NE * 8);
  unsigned short* xw1 = (unsigned short*)carve((size_t)N * 64 * 2);  // bf16, permuted
  unsigned short* h1  = (unsigned short*)carve((size_t)N * 64 * 2);  // bf16, permuted
  float* tmask = (float*)carve((size_t)M * 64 * 4);                  // fp32, permuted

  hipMemsetAsync(bucketTot, 0, (size_t)nbuck * 4, stream);

  // pack W1 + W2 first (tiny) so every GEMM uses packed bf16 B fragments
  k_pack<<<26, 256, 0, stream>>>(W1, packW1, W2, packW2);

  // k_pre: bucket hist || fuse MFMA (packed W1)
  const int fuseBlocks = (301 + 63) / 64;    // 16 rows/wave
  const int histBlocks = (E + 4095) / 4096;
  k_pre<<<histBlocks + fuseBlocks, 256, 0, stream>>>(
      Wlin, blin, packW1, WfuseB, histBlocks, ei, E, bucketTot, nbuck);

  // bucket scan || packWf  (block 0 scan; blocks 1..5 pack 2560 threads)
  k_scanB<<<6, 512, 0, stream>>>(bucketTot, nbuck, bucketBase, bucketRun,
                                 WfuseB, packWf);

  // scatter || doc GEMM
  const int docBlocks  = (ND + 63) / 64;
  k_sd<<<histBlocks + docBlocks, 256, 0, stream>>>(
      ei, ew, E, histBlocks, bucketRun, ebuf,
      doc, packW1, xw1, ND);

  // per-bucket CSR build || word GEMM
  const int wordBlocks = (NW + 63) / 64;     // 5000 waves (~20/CU)
  k_bw<<<nbuck + wordBlocks, 256, 0, stream>>>(
      ebuf, bucketBase, nbuck, N, offs, dis, entries,
      wordf, packWf, WfuseB + (size_t)300 * 64, xw1 + (size_t)ND * 64, NW);

  // layer-1 aggregation (+b1 via pi, relu) -> bf16 h1 (permuted)
  k_agg<<<(N + 7) / 8, 256, 0, stream>>>(xw1, entries, offs, dis, b1, h1, N);

  // layer-2: masked aggregation over h1, then project [M,64]@[64,64]+b2
  float* out0 = (float*)d_out;
  float* outY = out0 + (size_t)M * 64;
  k_agg2m<<<(M + 7) / 8, 256, 0, stream>>>(h1, entries, offs, dis, mask, y, tmask, outY, M);
  k_mfma_final<<<(M + 63) / 64, 256, 0, stream>>>(tmask, packW2, b2, out0, M);
}

// Round 8
// 317.631 us; speedup vs baseline: 1.3633x; 1.0317x over previous
//
#include <hip/hip_runtime.h>

// ---------------------------------------------------------------------------
// TextGCN (2-layer GCN, eval mode) on MI355X.
// Fusions:
//   * xw1_word = word @ (W_lin@W1) + (b_lin@W1)  (never materialize [N,768] x)
//   * layer 2: agg(h1@W2)[mask] == agg(h1)[mask] @ W2
// CSR BUILD = 2-LEVEL BUCKET SORT (no scattered-megaop atomics, r3 measured).
// GEMM: 16 rows/wave, CHUNK-deep A-load hoist, B always packed bf16 (r5/r6).
// PIPELINE BALANCE (r7): all kernels < 57us; loss is pairing imbalance.
//   Word GEMM (biggest chunk, ~45us) was alone with build in k_bw. Now:
//   doc GEMM moves into k_pre (needs only packW1); word GEMM splits 50/50
//   by rows between k_sd and k_bw. Each big dispatch ~= max(~25, ~25).
//   bucketTot zeroing folded into k_pack (drops hipMemsetAsync).
// PIPELINE:
//   k_pack(packW1||packW2||zero bucketTot) ->
//   k_pre(bucketHist || fuseGEMM || docGEMM) ->
//   k_scanB(bucket scan || packWf) ->
//   k_sd(scatter || wordGEMM rows[0,half)) ->
//   k_bw(bucketBuild || wordGEMM rows[half,NW)) ->
//   k_agg -> k_agg2m -> k_mfma_final
// xw1/h1 bf16 in PERMUTED column order pi(pos)=(pos&3)*16+(pos>>2) (coalesced
// 8B MFMA epilogue stores). b1 indexed via pi; packW2 k-rows permuted via pi.
// ebuf record: {src | (dst&255)<<17, w}  (src < 2^17 since N <= 131072).
// Fixed cost note: harness re-poisons 384MB ws (fillBufferAligned ~59us/iter
// at 81% HBM peak) -- not controllable from kernel code.
// ---------------------------------------------------------------------------

typedef __attribute__((ext_vector_type(8))) short short8;   // 8 bf16 = 4 VGPR
typedef __attribute__((ext_vector_type(4))) float float4v;  // MFMA C/D frag

__device__ __forceinline__ unsigned short f2bf(float f) {   // RNE f32->bf16
  unsigned u = __float_as_uint(f);
  return (unsigned short)((u + 0x7FFFu + ((u >> 16) & 1u)) >> 16);
}
__device__ __forceinline__ float bf2f(unsigned short u) {
  return __uint_as_float((unsigned)u << 16);
}
__device__ __forceinline__ int permcol(int p) {   // pi: pos -> true col
  return ((p & 3) << 4) | (p >> 2);
}

// pack W[K,64] fp32 -> bf16 fragment order: pack[((g*nk0+k0)*64+lane)*8+j]
// holds W[ksrc][(lane&15)+16g], ksrc = PERM ? pi(k) : k; zero past K.
template <bool PERM>
__device__ __forceinline__ void pack_w_body(const float* __restrict__ W, int K,
                                            int nk0, unsigned short* __restrict__ pack,
                                            int tid) {
  int lane = tid & 63;
  int rest = tid >> 6;
  int k0 = rest % nk0;
  int g = rest / nk0;
  int quad = lane >> 4;
  int n = (lane & 15) + g * 16;
  short8 v;
#pragma unroll
  for (int j = 0; j < 8; ++j) {
    int k = k0 * 32 + quad * 8 + j;
    int ks = PERM ? permcol(k) : k;
    float w = (k < K) ? W[(size_t)ks * 64 + n] : 0.f;
    v[j] = (short)f2bf(w);
  }
  *(short8*)(pack + (((size_t)(g * nk0 + k0) * 64 + lane) << 3)) = v;
}

// MFMA GEMM: out[R,64] = X[R,K(ldx)] @ W[K,64] (+bias). One wave = 16 rows.
// NK0/CHUNK compile-time: A-loads for CHUNK k0s issued back-to-back (deep
// MLP, few stalls/wave), then the chunk's convert+MFMA. B always from packed
// bf16 fragments (L2-hot).
template <bool LAST, bool BF16PERM, int NK0, int CHUNK>
__device__ __forceinline__ void mfma_gemm_body(
    const float* __restrict__ X, int ldx, const float* __restrict__ lastRow,
    const unsigned short* __restrict__ Wpack,
    int K, const float* __restrict__ bias,
    void* __restrict__ outv, int R, int waveIdx) {
  int r0 = waveIdx * 16;
  if (r0 >= R) return;
  const int lane = threadIdx.x & 63;
  const int quad = lane >> 4;
  const int m = lane & 15;
  const float* xrow = nullptr;
  {
    int row = r0 + m;
    if (row < R) xrow = (LAST && row == R - 1) ? lastRow : X + (size_t)row * ldx;
  }

  float4v acc[4];
#pragma unroll
  for (int g = 0; g < 4; ++g) acc[g] = (float4v){0.f, 0.f, 0.f, 0.f};

#pragma unroll
  for (int c0 = 0; c0 < NK0; c0 += CHUNK) {
    // ---- A-hoist: all CHUNK k0 loads, no dependent compute between ----
    float a[CHUNK][8];
#pragma unroll
    for (int cc = 0; cc < CHUNK; ++cc) {
      int kb = (c0 + cc) * 32 + quad * 8;
      if (xrow && kb + 8 <= K) {
        float4 v0 = *(const float4*)(xrow + kb);
        float4 v1 = *(const float4*)(xrow + kb + 4);
        a[cc][0] = v0.x; a[cc][1] = v0.y; a[cc][2] = v0.z; a[cc][3] = v0.w;
        a[cc][4] = v1.x; a[cc][5] = v1.y; a[cc][6] = v1.z; a[cc][7] = v1.w;
      } else {
#pragma unroll
        for (int j = 0; j < 8; ++j) {
          int k = kb + j;
          a[cc][j] = (xrow && k < K) ? xrow[k] : 0.f;
        }
      }
    }
    // ---- compute the chunk (packed bf16 B fragments) ----
#pragma unroll
    for (int cc = 0; cc < CHUNK; ++cc) {
      int k0 = c0 + cc;
      short8 bf[4];
#pragma unroll
      for (int g = 0; g < 4; ++g)
        bf[g] = *(const short8*)(Wpack + (((size_t)(g * NK0 + k0) * 64 + lane) << 3));
      short8 af;
#pragma unroll
      for (int j = 0; j < 8; ++j) af[j] = (short)f2bf(a[cc][j]);
#pragma unroll
      for (int g = 0; g < 4; ++g)
        acc[g] = __builtin_amdgcn_mfma_f32_16x16x32_bf16(af, bf[g], acc[g], 0, 0, 0);
    }
  }

  // ---- epilogue ----
  if (BF16PERM) {
    // lane m packs cols {m,16+m,32+m,48+m} of row r0+quad*4+j as 4 bf16 (8B)
    float b0 = bias ? bias[m] : 0.f;
    float b1 = bias ? bias[16 + m] : 0.f;
    float b2 = bias ? bias[32 + m] : 0.f;
    float b3 = bias ? bias[48 + m] : 0.f;
#pragma unroll
    for (int j = 0; j < 4; ++j) {
      int r = r0 + quad * 4 + j;
      if (r < R) {
        ushort4 pk;
        pk.x = f2bf(acc[0][j] + b0);
        pk.y = f2bf(acc[1][j] + b1);
        pk.z = f2bf(acc[2][j] + b2);
        pk.w = f2bf(acc[3][j] + b3);
        *(ushort4*)((unsigned short*)outv + ((size_t)r * 64 + m * 4)) = pk;
      }
    }
  } else {
#pragma unroll
    for (int g = 0; g < 4; ++g) {
      float b = bias ? bias[g * 16 + m] : 0.f;
#pragma unroll
      for (int reg = 0; reg < 4; ++reg) {
        int r = r0 + quad * 4 + reg;   // C/D: col=lane&15, row=quad*4+reg
        if (r < R) ((float*)outv)[(size_t)r * 64 + g * 16 + m] = acc[g][reg] + b;
      }
    }
  }
}

// k_pack: [24) pack W1; [+2) pack W2 (permuted k); [+1) zero bucketTot.
__global__ __launch_bounds__(256) void k_pack(
    const float* __restrict__ W1, unsigned short* __restrict__ packW1,
    const float* __restrict__ W2, unsigned short* __restrict__ packW2,
    int* __restrict__ bucketTot, int nbuck) {
  int b = blockIdx.x;
  int t = threadIdx.x;
  if (b < 24) { pack_w_body<false>(W1, 768, 24, packW1, b * 256 + t); return; }
  b -= 24;
  if (b < 2) { pack_w_body<true>(W2, 64, 2, packW2, b * 256 + t); return; }
  for (int i = t; i < nbuck + 2; i += 256) bucketTot[i] = 0;
}

// k_pre: [histBlocks) bucket histogram (LDS, flush <=nbuck atomics/block);
//        [+fuseBlocks) fuse GEMM [Wlin;blin]@W1 -> WfuseB (packed W1);
//        rest: doc GEMM (packed W1) -> xw1 rows [0,ND).
__global__ __launch_bounds__(256) void k_pre(
    const float* __restrict__ Wlin, const float* __restrict__ blin,
    const unsigned short* __restrict__ packW1, float* __restrict__ WfuseB,
    int histBlocks, int fuseBlocks,
    const int* __restrict__ ei, int E, int* __restrict__ bucketTot, int nbuck,
    const float* __restrict__ doc, unsigned short* __restrict__ xw1, int ND) {
  int b = blockIdx.x;
  int t = threadIdx.x;
  if (b < histBlocks) {
    __shared__ int h[512];
    h[t] = 0; h[t + 256] = 0;
    __syncthreads();
    int e0 = b * 4096;
#pragma unroll 4
    for (int i = 0; i < 16; ++i) {
      int e = e0 + t + i * 256;
      if (e < E) atomicAdd(&h[ei[E + e] >> 8], 1);
    }
    __syncthreads();
    if (t < nbuck && h[t]) atomicAdd(bucketTot + t, h[t]);
    if (t + 256 < nbuck && h[t + 256]) atomicAdd(bucketTot + t + 256, h[t + 256]);
    return;
  }
  b -= histBlocks;
  if (b < fuseBlocks) {
    mfma_gemm_body<true, false, 24, 8>(Wlin, 768, blin, packW1, 768,
                                       nullptr, WfuseB, 301, b * 4 + (t >> 6));
    return;
  }
  b -= fuseBlocks;
  mfma_gemm_body<false, true, 24, 8>(doc, 768, nullptr, packW1, 768,
                                     nullptr, xw1, ND, b * 4 + (t >> 6));
}

// k_scanB: block 0 = exclusive scan of bucketTot -> bucketBase/bucketRun;
//          blocks 1..5 = pack WfuseB (rows 0..299) -> bf16 fragments.
__global__ __launch_bounds__(512) void k_scanB(
    const int* __restrict__ bucketTot, int nbuck,
    int* __restrict__ bucketBase, int* __restrict__ bucketRun,
    const float* __restrict__ WfuseB, unsigned short* __restrict__ packWf) {
  int t = threadIdx.x;
  if (blockIdx.x > 0) {
    pack_w_body<false>(WfuseB, 300, 10, packWf, ((int)blockIdx.x - 1) * 512 + t);
    return;
  }
  __shared__ int s[512];
  int v = (t < nbuck) ? bucketTot[t] : 0;
  s[t] = v; __syncthreads();
  for (int off = 1; off < 512; off <<= 1) {
    int x = (t >= off) ? s[t - off] : 0;
    __syncthreads();
    s[t] += x;
    __syncthreads();
  }
  if (t < nbuck) {
    int ex = s[t] - v;
    bucketBase[t] = ex;
    bucketRun[t] = ex;
  }
  if (t == nbuck - 1) bucketBase[nbuck] = s[t];   // = E
}

// k_sd: [scatBlocks) scatter edges into bucket-grouped ebuf (LDS ranks, one
// run-reservation atomic per non-empty (block,bucket)); rest: word GEMM
// rows [0, NWsd) (packed WfuseB fragments).
__global__ __launch_bounds__(256) void k_sd(
    const int* __restrict__ ei, const float* __restrict__ ew, int E,
    int scatBlocks, int* __restrict__ bucketRun, int2* __restrict__ ebuf,
    const float* __restrict__ wordf, const unsigned short* __restrict__ packWf,
    const float* __restrict__ bfuse, unsigned short* __restrict__ xw1word, int NWsd) {
  int b = blockIdx.x;
  int t = threadIdx.x;
  if (b >= scatBlocks) {
    mfma_gemm_body<false, true, 10, 5>(wordf, 300, nullptr, packWf, 300,
                                       bfuse, xw1word, NWsd, (b - scatBlocks) * 4 + (t >> 6));
    return;
  }
  __shared__ int h[512];
  __shared__ int base[512];
  __shared__ int cur[512];
  h[t] = 0; h[t + 256] = 0;
  __syncthreads();
  int e0 = b * 4096;
#pragma unroll 4
  for (int i = 0; i < 16; ++i) {
    int e = e0 + t + i * 256;
    if (e < E) atomicAdd(&h[ei[E + e] >> 8], 1);
  }
  __syncthreads();
#pragma unroll
  for (int k = t; k < 512; k += 256) {
    if (h[k]) base[k] = atomicAdd(bucketRun + k, h[k]);
    cur[k] = 0;
  }
  __syncthreads();
#pragma unroll 4
  for (int i = 0; i < 16; ++i) {
    int e = e0 + t + i * 256;
    if (e < E) {
      int d = ei[E + e];
      int bk = d >> 8;
      int r = base[bk] + atomicAdd(&cur[bk], 1);
      ebuf[r] = make_int2(ei[e] | ((d & 255) << 17), __float_as_int(ew[e]));
    }
  }
}

// k_bw: [nbuck) per-bucket CSR build (LDS cnt/wdeg/scan -> contiguous
// entries slice + offs + dis); rest: word GEMM rows [NWsd, NW) via
// pre-offset pointers.
__global__ __launch_bounds__(256) void k_bw(
    const int2* __restrict__ ebuf, const int* __restrict__ bucketBase,
    int nbuck, int N, int* __restrict__ offs, float* __restrict__ dis,
    int2* __restrict__ entries,
    const float* __restrict__ wordf2, const unsigned short* __restrict__ packWf,
    const float* __restrict__ bfuse, unsigned short* __restrict__ xw1word2, int NW2) {
  int b = blockIdx.x;
  int t = threadIdx.x;
  if (b >= nbuck) {
    mfma_gemm_body<false, true, 10, 5>(wordf2, 300, nullptr, packWf, 300,
                                       bfuse, xw1word2, NW2, (b - nbuck) * 4 + (t >> 6));
    return;
  }
  __shared__ int scnt[256];
  __shared__ float swd[256];
  __shared__ int sscan[256];
  __shared__ int scur[256];
  int node0 = b << 8;
  int nn = min(256, N - node0);
  int estart = bucketBase[b], eend = bucketBase[b + 1];
  scnt[t] = (t < nn) ? 1 : 0;          // self loop
  swd[t] = (t < nn) ? 1.f : 0.f;       // self weight
  __syncthreads();
  for (int p = estart + t; p < eend; p += 256) {
    int2 e = ebuf[p];
    int low = (e.x >> 17) & 255;
    atomicAdd(&scnt[low], 1);
    atomicAdd(&swd[low], __int_as_float(e.y));
  }
  __syncthreads();
  int v = scnt[t];
  sscan[t] = v; __syncthreads();
  for (int off = 1; off < 256; off <<= 1) {
    int x = (t >= off) ? sscan[t - off] : 0;
    __syncthreads();
    sscan[t] += x;
    __syncthreads();
  }
  int excl = sscan[t] - v;
  int entriesBase = estart + node0;    // edges-before + selfs-before
  if (t < nn) {
    offs[node0 + t] = entriesBase + excl;
    dis[node0 + t] = rsqrtf(fmaxf(swd[t], 1e-12f));
    entries[entriesBase + excl] = make_int2(node0 + t, __float_as_int(1.0f));
  }
  scur[t] = excl + 1;
  if (t == 0 && b == nbuck - 1) offs[N] = entriesBase + (eend - estart) + nn;
  __syncthreads();
  for (int p = estart + t; p < eend; p += 256) {
    int2 e = ebuf[p];
    int low = (e.x >> 17) & 255;
    int r = atomicAdd(&scur[low], 1);
    entries[entriesBase + r] = make_int2(e.x & 0x1FFFF, e.y);
  }
}

// half-wave gather-accumulate: 32 lanes, each lane covers 2 cols (ushort2).
// entries hold RAW w -> multiply dis[src] per entry (broadcast, L2-hot).
__device__ __forceinline__ void row_gather2(const unsigned short* __restrict__ xin,
                                            const int2* __restrict__ entries,
                                            const float* __restrict__ dis,
                                            int p, int pe, int l32,
                                            float& ra0, float& ra1) {
  float a0 = 0.f, a1 = 0.f;
  for (; p + 8 <= pe; p += 8) {
    int2 e[8];
#pragma unroll
    for (int j = 0; j < 8; ++j) e[j] = entries[p + j];
    unsigned x[8];
    float ds[8];
#pragma unroll
    for (int j = 0; j < 8; ++j) {
      x[j] = *(const unsigned*)(xin + ((size_t)e[j].x << 6) + (l32 << 1));
      ds[j] = dis[e[j].x];
    }
#pragma unroll
    for (int j = 0; j < 8; ++j) {
      float w = __int_as_float(e[j].y) * ds[j];
      a0 = fmaf(bf2f((unsigned short)(x[j] & 0xffffu)), w, a0);
      a1 = fmaf(bf2f((unsigned short)(x[j] >> 16)), w, a1);
    }
  }
  if (p + 4 <= pe) {
    int2 e[4];
#pragma unroll
    for (int j = 0; j < 4; ++j) e[j] = entries[p + j];
    unsigned x[4];
    float ds[4];
#pragma unroll
    for (int j = 0; j < 4; ++j) {
      x[j] = *(const unsigned*)(xin + ((size_t)e[j].x << 6) + (l32 << 1));
      ds[j] = dis[e[j].x];
    }
#pragma unroll
    for (int j = 0; j < 4; ++j) {
      float w = __int_as_float(e[j].y) * ds[j];
      a0 = fmaf(bf2f((unsigned short)(x[j] & 0xffffu)), w, a0);
      a1 = fmaf(bf2f((unsigned short)(x[j] >> 16)), w, a1);
    }
    p += 4;
  }
  for (; p < pe; ++p) {
    int2 e = entries[p];
    unsigned x = *(const unsigned*)(xin + ((size_t)e.x << 6) + (l32 << 1));
    float w = __int_as_float(e.y) * dis[e.x];
    a0 = fmaf(bf2f((unsigned short)(x & 0xffffu)), w, a0);
    a1 = fmaf(bf2f((unsigned short)(x >> 16)), w, a1);
  }
  ra0 = a0; ra1 = a1;
}

// layer-1 aggregation: half-wave per node, ushort2 out (permuted pos layout)
__global__ void k_agg(const unsigned short* __restrict__ xin, const int2* __restrict__ entries,
                      const int* __restrict__ offs, const float* __restrict__ dis,
                      const float* __restrict__ bias, unsigned short* __restrict__ xout, int N) {
  const int tid = threadIdx.x;
  const int l32 = tid & 31;
  int i = blockIdx.x * 8 + (tid >> 5);
  if (i >= N) return;
  float a0, a1;
  row_gather2(xin, entries, dis, offs[i], offs[i + 1], l32, a0, a1);
  float d = dis[i];
  a0 = fmaxf(fmaf(a0, d, bias[permcol(2 * l32)]), 0.f);
  a1 = fmaxf(fmaf(a1, d, bias[permcol(2 * l32 + 1)]), 0.f);
  ushort2 pk;
  pk.x = f2bf(a0);
  pk.y = f2bf(a1);
  *(ushort2*)(xout + ((size_t)i << 6) + (l32 << 1)) = pk;
}

// masked layer-2 aggregation: half-wave per masked node, fp32 out + y[mask]
__global__ void k_agg2m(const unsigned short* __restrict__ xin, const int2* __restrict__ entries,
                        const int* __restrict__ offs, const float* __restrict__ dis,
                        const int* __restrict__ mask, const int* __restrict__ y,
                        float* __restrict__ tout, float* __restrict__ outY, int M) {
  const int tid = threadIdx.x;
  const int l32 = tid & 31;
  int o = blockIdx.x * 8 + (tid >> 5);
  if (o >= M) return;
  int i = mask[o];
  float a0, a1;
  row_gather2(xin, entries, dis, offs[i], offs[i + 1], l32, a0, a1);
  float d = dis[i];
  float2 pk;
  pk.x = a0 * d;
  pk.y = a1 * d;
  *(float2*)(tout + ((size_t)o << 6) + (l32 << 1)) = pk;
  if (l32 == 0) outY[o] = (float)y[i];
}

// final projection [M,64]@[64,64]+b2 via MFMA (permuted-k packed W2), fp32 out
__global__ __launch_bounds__(256) void k_mfma_final(
    const float* __restrict__ X, const unsigned short* __restrict__ packW2,
    const float* __restrict__ b2, float* __restrict__ out, int M) {
  mfma_gemm_body<false, false, 2, 2>(X, 64, nullptr, packW2, 64,
                                     b2, out, M, blockIdx.x * 4 + (threadIdx.x >> 6));
}

extern "C" void kernel_launch(void* const* d_in, const int* in_sizes, int n_in,
                              void* d_out, int out_size, void* d_ws, size_t ws_size,
                              hipStream_t stream) {
  const float* doc   = (const float*)d_in[0];
  const float* wordf = (const float*)d_in[1];
  const float* ew    = (const float*)d_in[2];
  const float* Wlin  = (const float*)d_in[3];
  const float* blin  = (const float*)d_in[4];
  const float* W1    = (const float*)d_in[5];
  const float* b1    = (const float*)d_in[6];
  const float* W2    = (const float*)d_in[7];
  const float* b2    = (const float*)d_in[8];
  const int*   ei    = (const int*)d_in[9];
  const int*   mask  = (const int*)d_in[10];
  const int*   y     = (const int*)d_in[11];

  const int E  = in_sizes[2];
  const int M  = in_sizes[10];
  const int ND = in_sizes[0] / 768;
  const int NW = in_sizes[1] / 300;
  const int N  = ND + NW;
  const int NE = N + E;
  const int nbuck = (N + 255) >> 8;          // <= 512 (N <= 131072)

  // workspace carve (aligned 256B)
  char* p = (char*)d_ws;
  auto carve = [&](size_t bytes) -> void* {
    void* q = (void*)p;
    p += (bytes + 255) & ~(size_t)255;
    return q;
  };
  float*          WfuseB = (float*)carve(301 * 64 * 4);
  unsigned short* packW1 = (unsigned short*)carve((size_t)4 * 24 * 64 * 8 * 2);
  unsigned short* packW2 = (unsigned short*)carve((size_t)4 * 2 * 64 * 8 * 2);
  unsigned short* packWf = (unsigned short*)carve((size_t)4 * 10 * 64 * 8 * 2);
  float* dis       = (float*)carve((size_t)N * 4);
  int*   offs      = (int*)carve(((size_t)N + 1) * 4);
  int*   bucketTot = (int*)carve((size_t)(nbuck + 2) * 4);
  int*   bucketBase= (int*)carve((size_t)(nbuck + 2) * 4);
  int*   bucketRun = (int*)carve((size_t)(nbuck + 2) * 4);
  int2*  ebuf      = (int2*)carve((size_t)E * 8);
  int2*  entries   = (int2*)carve((size_t)NE * 8);
  unsigned short* xw1 = (unsigned short*)carve((size_t)N * 64 * 2);  // bf16, permuted
  unsigned short* h1  = (unsigned short*)carve((size_t)N * 64 * 2);  // bf16, permuted
  float* tmask = (float*)carve((size_t)M * 64 * 4);                  // fp32, permuted

  // pack W1 + W2 + zero bucketTot (replaces memset launch)
  k_pack<<<27, 256, 0, stream>>>(W1, packW1, W2, packW2, bucketTot, nbuck);

  // k_pre: bucket hist || fuse MFMA || doc MFMA (both packed W1)
  const int fuseBlocks = (301 + 63) / 64;
  const int docBlocks  = (ND + 63) / 64;
  const int histBlocks = (E + 4095) / 4096;
  k_pre<<<histBlocks + fuseBlocks + docBlocks, 256, 0, stream>>>(
      Wlin, blin, packW1, WfuseB, histBlocks, fuseBlocks,
      ei, E, bucketTot, nbuck, doc, xw1, ND);

  // bucket scan || packWf  (block 0 scan; blocks 1..5 pack 2560 threads)
  k_scanB<<<6, 512, 0, stream>>>(bucketTot, nbuck, bucketBase, bucketRun,
                                 WfuseB, packWf);

  // word GEMM split 50/50 between k_sd and k_bw (rows are independent)
  const int wordBlocks = (NW + 63) / 64;
  const int wsdBlocks  = wordBlocks / 2;
  const int wsdRows    = wsdBlocks * 64;
  unsigned short* xw1word = xw1 + (size_t)ND * 64;
  const float*    bfuse   = WfuseB + (size_t)300 * 64;

  // scatter || word GEMM rows [0, wsdRows)
  k_sd<<<histBlocks + wsdBlocks, 256, 0, stream>>>(
      ei, ew, E, histBlocks, bucketRun, ebuf,
      wordf, packWf, bfuse, xw1word, wsdRows);

  // per-bucket CSR build || word GEMM rows [wsdRows, NW)
  k_bw<<<nbuck + (wordBlocks - wsdBlocks), 256, 0, stream>>>(
      ebuf, bucketBase, nbuck, N, offs, dis, entries,
      wordf + (size_t)wsdRows * 300, packWf, bfuse,
      xw1word + (size_t)wsdRows * 64, NW - wsdRows);

  // layer-1 aggregation (+b1 via pi, relu) -> bf16 h1 (permuted)
  k_agg<<<(N + 7) / 8, 256, 0, stream>>>(xw1, entries, offs, dis, b1, h1, N);

  // layer-2: masked aggregation over h1, then project [M,64]@[64,64]+b2
  float* out0 = (float*)d_out;
  float* outY = out0 + (size_t)M * 64;
  k_agg2m<<<(M + 7) / 8, 256, 0, stream>>>(h1, entries, offs, dis, mask, y, tmask, outY, M);
  k_mfma_final<<<(M + 63) / 64, 256, 0, stream>>>(tmask, packW2, b2, out0, M);
}